// Round 1
// baseline (800.972 us; speedup 1.0000x reference)
//
#include <hip/hip_runtime.h>
#include <hip/hip_bf16.h>

// GAT 3-layer forward on MI355X. All intermediates fp32 in d_ws.
// Dtype of d_in/d_out (bf16 vs fp32) auto-detected on device (flag in ws).

#define THREADS 256

// ---------------- dtype detection ----------------
// If input x is fp32, its low 16-bit halves reinterpret as bf16 with uniform
// random exponents -> ~43% "extreme". Real bf16 N(0,1) data -> ~0%.
__global__ void detect_kernel(const unsigned short* __restrict__ x, int n, int* flag) {
    __shared__ int cnt;
    if (threadIdx.x == 0) cnt = 0;
    __syncthreads();
    int local = 0;
    for (int i = threadIdx.x; i < n; i += THREADS) {
        unsigned ex = (x[i] >> 7) & 0xFF;
        if (ex == 0xFF || ex >= 134 || (ex > 0 && ex <= 100)) local++;
    }
    atomicAdd(&cnt, local);
    __syncthreads();
    if (threadIdx.x == 0) *flag = (cnt * 8 > n) ? 0 : 1;  // 1 = bf16
}

// ---------------- input conversion ----------------
struct ConvArgs {
    const void* src[22];
    float* dst[22];
    int prefix[23];
};

__global__ void convert_kernel(ConvArgs a, const int* __restrict__ flag, int total) {
    int i = blockIdx.x * THREADS + threadIdx.x;
    if (i >= total) return;
    bool isbf = (*flag != 0);
    int lo = 0;
    while (i >= a.prefix[lo + 1]) ++lo;
    int off = i - a.prefix[lo];
    float v;
    if (isbf) {
        unsigned short u = ((const unsigned short*)a.src[lo])[off];
        v = __uint_as_float(((unsigned)u) << 16);
    } else {
        v = ((const float*)a.src[lo])[off];
    }
    a.dst[lo][off] = v;
}

// ---------------- CSR build ----------------
__global__ void count_kernel(const int* __restrict__ ei, int* __restrict__ deg, int E, int N) {
    int e = blockIdx.x * THREADS + threadIdx.x;
    if (e >= E + N) return;
    int d = (e < E) ? ei[E + e] : (e - E);
    atomicAdd(&deg[d], 1);
}

__global__ __launch_bounds__(1024) void scan_kernel(const int* __restrict__ deg,
                                                    int* __restrict__ row_ptr, int N) {
    __shared__ int sh[1024];
    int tid = threadIdx.x;
    int running = 0;
    for (int basei = 0; basei < N; basei += 8192) {
        int vals[8];
        int sum = 0;
        int b0 = basei + tid * 8;
#pragma unroll
        for (int i = 0; i < 8; i++) {
            int idx = b0 + i;
            int v = (idx < N) ? deg[idx] : 0;
            vals[i] = v;
            sum += v;
        }
        sh[tid] = sum;
        __syncthreads();
#pragma unroll
        for (int offv = 1; offv < 1024; offv <<= 1) {
            int t = (tid >= offv) ? sh[tid - offv] : 0;
            __syncthreads();
            sh[tid] += t;
            __syncthreads();
        }
        int excl = running + (tid ? sh[tid - 1] : 0);
        int tot = sh[1023];
#pragma unroll
        for (int i = 0; i < 8; i++) {
            int idx = b0 + i;
            excl += vals[i];
            if (idx < N) row_ptr[idx + 1] = excl;
        }
        running += tot;
        __syncthreads();
    }
    if (tid == 0) row_ptr[0] = 0;
}

__global__ void copy_kernel(const int* __restrict__ rp, int* __restrict__ pos, int N) {
    int n = blockIdx.x * THREADS + threadIdx.x;
    if (n < N) pos[n] = rp[n];
}

__global__ void scatter_kernel(const int* __restrict__ ei, int* __restrict__ pos,
                               int* __restrict__ csr, int E, int N) {
    int e = blockIdx.x * THREADS + threadIdx.x;
    if (e >= E + N) return;
    int s, d;
    if (e < E) { s = ei[e]; d = ei[E + e]; }
    else { s = e - E; d = s; }
    int p = atomicAdd(&pos[d], 1);
    csr[p] = s;
}

// ---------------- GEMM [N,128] @ [128,128], fused e_src/e_dst epilogue ----------------
__global__ __launch_bounds__(256) void gemm128_kernel(
    const float* __restrict__ A, const float* __restrict__ W,
    const float* __restrict__ asv, const float* __restrict__ adv,
    float* __restrict__ out, float* __restrict__ es, float* __restrict__ ed, int N) {
    __shared__ __align__(16) float Ws[128 * 128];
    __shared__ float As[8][132];
    int tid = threadIdx.x;
    for (int i = tid; i < 128 * 128; i += 256) Ws[i] = W[i];
    int tx = tid & 31;
    int ty = tid >> 5;  // 0..7
    int colBase = tx * 4;
    int rowBase = blockIdx.x * 64;
    bool doE = (asv != nullptr);
    float4 av = make_float4(0.f, 0.f, 0.f, 0.f), dv = make_float4(0.f, 0.f, 0.f, 0.f);
    if (doE) {
        av = *(const float4*)(asv + colBase);
        dv = *(const float4*)(adv + colBase);
    }
    for (int it = 0; it < 8; ++it) {
        int row0 = rowBase + it * 8;
        __syncthreads();
        {
            int j = tid * 4;
            int r = j >> 7, cc = j & 127;
            int row = row0 + r;
            float4 v = make_float4(0.f, 0.f, 0.f, 0.f);
            if (row < N) v = *(const float4*)(A + (size_t)row * 128 + cc);
            As[r][cc] = v.x; As[r][cc + 1] = v.y; As[r][cc + 2] = v.z; As[r][cc + 3] = v.w;
        }
        __syncthreads();
        float4 acc = make_float4(0.f, 0.f, 0.f, 0.f);
#pragma unroll
        for (int k = 0; k < 128; ++k) {
            float a = As[ty][k];
            float4 wv = *(const float4*)(Ws + k * 128 + colBase);
            acc.x = fmaf(a, wv.x, acc.x);
            acc.y = fmaf(a, wv.y, acc.y);
            acc.z = fmaf(a, wv.z, acc.z);
            acc.w = fmaf(a, wv.w, acc.w);
        }
        int row = row0 + ty;
        if (row < N) *(float4*)(out + (size_t)row * 128 + colBase) = acc;
        if (doE) {
            float s = acc.x * av.x + acc.y * av.y + acc.z * av.z + acc.w * av.w;
            float d = acc.x * dv.x + acc.y * dv.y + acc.z * dv.z + acc.w * dv.w;
#pragma unroll
            for (int o = 1; o < 8; o <<= 1) {
                s += __shfl_xor(s, o, 64);
                d += __shfl_xor(d, o, 64);
            }
            if ((tx & 7) == 0 && row < N) {
                int h = tx >> 3;
                es[row * 4 + h] = s;
                ed[row * 4 + h] = d;
            }
        }
    }
}

// ---------------- aggregation, layers 1-2 (H=4, C=32) ----------------
__global__ __launch_bounds__(256) void agg128_kernel(
    const float* __restrict__ xw, const float* __restrict__ es, const float* __restrict__ ed,
    const int* __restrict__ row_ptr, const int* __restrict__ csr,
    const float* __restrict__ bias, float* __restrict__ out, int N) {
    int w = threadIdx.x >> 6;
    int lane = threadIdx.x & 63;
    int gw = blockIdx.x * 4 + w;
    int node = gw >> 1;
    if (node >= N) return;
    int hp = gw & 1;
    int h = hp * 2 + (lane >> 5);
    int c = lane & 31;
    int col = h * 32 + c;
    int start = row_ptr[node], end = row_ptr[node + 1];
    float edl = ed[node * 4 + h];
    float m = -1e30f;
    for (int j = start; j < end; ++j) {
        int s = csr[j];
        float e = es[s * 4 + h] + edl;
        e = e > 0.f ? e : 0.2f * e;
        m = fmaxf(m, e);
    }
    float den = 0.f, acc = 0.f;
    for (int j = start; j < end; ++j) {
        int s = csr[j];
        float e = es[s * 4 + h] + edl;
        e = e > 0.f ? e : 0.2f * e;
        float wg = __expf(e - m);
        den += wg;
        acc += wg * xw[(size_t)s * 128 + col];
    }
    out[(size_t)node * 128 + col] = acc / den + bias[col];
}

// ---------------- BN + residual + ELU ----------------
__global__ void pw_kernel(const float* __restrict__ gout, const float* __restrict__ res,
                          const float* __restrict__ g, const float* __restrict__ be,
                          const float* __restrict__ mm, const float* __restrict__ vv,
                          float* __restrict__ out, int total) {
    int i = blockIdx.x * THREADS + threadIdx.x;
    if (i >= total) return;
    int c = i & 127;
    float val = (gout[i] - mm[c]) * rsqrtf(vv[c] + 1e-5f) * g[c] + be[c] + res[i];
    out[i] = val > 0.f ? val : expm1f(val);
}

// ---------------- layer 3: GEMM [N,128]@[128,40] ----------------
__global__ __launch_bounds__(256) void gemm40_kernel(const float* __restrict__ A,
                                                     const float* __restrict__ W,
                                                     float* __restrict__ out, int N) {
    __shared__ float Ws[128 * 40];
    for (int i = threadIdx.x; i < 128 * 40; i += 256) Ws[i] = W[i];
    __syncthreads();
    int idx = blockIdx.x * 256 + threadIdx.x;
    if (idx >= N * 40) return;
    int n = idx / 40, c = idx % 40;
    const float* a = A + (size_t)n * 128;
    float acc = 0.f;
#pragma unroll 8
    for (int k = 0; k < 128; ++k) acc = fmaf(a[k], Ws[k * 40 + c], acc);
    out[idx] = acc;
}

__global__ void esed40_kernel(const float* __restrict__ xw3, const float* __restrict__ as3,
                              const float* __restrict__ ad3, float* __restrict__ es3,
                              float* __restrict__ ed3, int N) {
    int n = blockIdx.x * THREADS + threadIdx.x;
    if (n >= N) return;
    float s = 0.f, d = 0.f;
    const float* a = xw3 + (size_t)n * 40;
#pragma unroll
    for (int c = 0; c < 40; ++c) {
        float v = a[c];
        s = fmaf(v, as3[c], s);
        d = fmaf(v, ad3[c], d);
    }
    es3[n] = s;
    ed3[n] = d;
}

// ---------------- layer 3 aggregation (H=1, C=40), writes d_out ----------------
__global__ __launch_bounds__(256) void agg40_kernel(
    const float* __restrict__ xw3, const float* __restrict__ es3, const float* __restrict__ ed3,
    const int* __restrict__ row_ptr, const int* __restrict__ csr, const float* __restrict__ b3,
    void* __restrict__ out, const int* __restrict__ flag, int N) {
    int w = threadIdx.x >> 6;
    int lane = threadIdx.x & 63;
    int node = blockIdx.x * 4 + w;
    if (node >= N) return;
    float edl = ed3[node];
    int start = row_ptr[node], end = row_ptr[node + 1];
    float m = -1e30f;
    for (int j = start; j < end; ++j) {
        float e = es3[csr[j]] + edl;
        e = e > 0.f ? e : 0.2f * e;
        m = fmaxf(m, e);
    }
    float den = 0.f, acc = 0.f;
    int c = lane < 40 ? lane : 0;
    for (int j = start; j < end; ++j) {
        int s = csr[j];
        float e = es3[s] + edl;
        e = e > 0.f ? e : 0.2f * e;
        float wg = __expf(e - m);
        den += wg;
        acc += wg * xw3[(size_t)s * 40 + c];
    }
    if (lane < 40) {
        float v = acc / den + b3[lane];
        if (*flag)
            ((__hip_bfloat16*)out)[(size_t)node * 40 + lane] = __float2bfloat16(v);
        else
            ((float*)out)[(size_t)node * 40 + lane] = v;
    }
}

extern "C" void kernel_launch(void* const* d_in, const int* in_sizes, int n_in,
                              void* d_out, int out_size, void* d_ws, size_t ws_size,
                              hipStream_t stream) {
    (void)n_in; (void)out_size; (void)ws_size;
    const int N = in_sizes[0] / 128;
    const int E = in_sizes[1] / 2;
    const int EPN = E + N;
    char* base = (char*)d_ws;
    size_t off = 0;
    auto alloc = [&](size_t bytes) -> char* {
        char* p = base + off;
        off = (off + bytes + 255) & ~(size_t)255;
        return p;
    };
    int* flag = (int*)alloc(4);
    int* deg = (int*)alloc((size_t)N * 4);
    int* row_ptr = (int*)alloc((size_t)(N + 1) * 4);
    int* pos = (int*)alloc((size_t)N * 4);
    int* csr = (int*)alloc((size_t)EPN * 4);
    float* wc = (float*)alloc((size_t)56184 * 4);
    float* xf = (float*)alloc((size_t)N * 128 * 4);   // x, later reused as h2
    float* h1 = (float*)alloc((size_t)N * 128 * 4);
    float* xw = (float*)alloc((size_t)N * 128 * 4);
    float* gout = (float*)alloc((size_t)N * 128 * 4);
    float* es = (float*)alloc((size_t)N * 4 * 4);
    float* ed = (float*)alloc((size_t)N * 4 * 4);

    const int* ei = (const int*)d_in[1];

    // fp32 weight region layout (float offsets)
    float* W1 = wc;            float* AS1 = wc + 16384; float* AD1 = wc + 16512; float* B1 = wc + 16640;
    float* W2 = wc + 16768;    float* AS2 = wc + 33152; float* AD2 = wc + 33280; float* B2 = wc + 33408;
    float* W3 = wc + 33536;    float* AS3 = wc + 38656; float* AD3 = wc + 38696; float* B3 = wc + 38736;
    float* WR = wc + 38776;
    float* G1 = wc + 55160; float* BE1 = wc + 55288; float* M1 = wc + 55416; float* V1 = wc + 55544;
    float* G2 = wc + 55672; float* BE2 = wc + 55800; float* M2 = wc + 55928; float* V2 = wc + 56056;

    hipMemsetAsync(deg, 0, (size_t)N * 4, stream);
    detect_kernel<<<1, THREADS, 0, stream>>>((const unsigned short*)d_in[0], 4096, flag);

    ConvArgs ca;
    const int idxs[22] = {0, 2, 3, 4, 5, 6, 7, 8, 9, 10, 11, 12, 13, 14, 15, 16, 17, 18, 19, 20, 21, 22};
    float* dsts[22] = {xf, W1, AS1, AD1, B1, W2, AS2, AD2, B2, W3, AS3, AD3, B3, WR,
                       G1, BE1, M1, V1, G2, BE2, M2, V2};
    int p = 0;
    for (int t = 0; t < 22; t++) {
        ca.src[t] = d_in[idxs[t]];
        ca.dst[t] = dsts[t];
        ca.prefix[t] = p;
        p += in_sizes[idxs[t]];
    }
    ca.prefix[22] = p;
    int total = p;
    convert_kernel<<<(total + THREADS - 1) / THREADS, THREADS, 0, stream>>>(ca, flag, total);

    count_kernel<<<(EPN + THREADS - 1) / THREADS, THREADS, 0, stream>>>(ei, deg, E, N);
    scan_kernel<<<1, 1024, 0, stream>>>(deg, row_ptr, N);
    copy_kernel<<<(N + THREADS - 1) / THREADS, THREADS, 0, stream>>>(row_ptr, pos, N);
    scatter_kernel<<<(EPN + THREADS - 1) / THREADS, THREADS, 0, stream>>>(ei, pos, csr, E, N);

    int gemmGrid = (N + 63) / 64;
    int aggGrid = (2 * N + 3) / 4;
    int pwGrid = (N * 128 + THREADS - 1) / THREADS;

    // layer 1
    gemm128_kernel<<<gemmGrid, 256, 0, stream>>>(xf, W1, AS1, AD1, xw, es, ed, N);
    agg128_kernel<<<aggGrid, 256, 0, stream>>>(xw, es, ed, row_ptr, csr, B1, gout, N);
    gemm128_kernel<<<gemmGrid, 256, 0, stream>>>(xf, WR, nullptr, nullptr, xw, nullptr, nullptr, N);
    pw_kernel<<<pwGrid, THREADS, 0, stream>>>(gout, xw, G1, BE1, M1, V1, h1, N * 128);
    // layer 2
    gemm128_kernel<<<gemmGrid, 256, 0, stream>>>(h1, W2, AS2, AD2, xw, es, ed, N);
    agg128_kernel<<<aggGrid, 256, 0, stream>>>(xw, es, ed, row_ptr, csr, B2, gout, N);
    pw_kernel<<<pwGrid, THREADS, 0, stream>>>(gout, h1, G2, BE2, M2, V2, xf, N * 128);
    // layer 3 (h2 lives in xf)
    gemm40_kernel<<<(N * 40 + 255) / 256, 256, 0, stream>>>(xf, W3, xw, N);
    esed40_kernel<<<(N + THREADS - 1) / THREADS, THREADS, 0, stream>>>(xw, AS3, AD3, es, ed, N);
    agg40_kernel<<<(N + 3) / 4, 256, 0, stream>>>(xw, es, ed, row_ptr, csr, B3, d_out, flag, N);
}

// Round 2
// 466.406 us; speedup vs baseline: 1.7173x; 1.7173x over previous
//
#include <hip/hip_runtime.h>
#include <hip/hip_bf16.h>

#define THREADS 256

typedef __attribute__((ext_vector_type(8))) short bfrag;     // 8 bf16 = 4 VGPR
typedef __attribute__((ext_vector_type(4))) float f32x4;     // MFMA accumulator

__device__ inline unsigned short f2b(float v) {
    __hip_bfloat16 b = __float2bfloat16(v);
    return *reinterpret_cast<unsigned short*>(&b);
}
__device__ inline float b2f(unsigned short u) {
    return __uint_as_float(((unsigned)u) << 16);
}

// ---------------- dtype detection (bf16 vs fp32 inputs) ----------------
__global__ void detect_kernel(const unsigned short* __restrict__ x, int n, int* flag) {
    __shared__ int cnt;
    if (threadIdx.x == 0) cnt = 0;
    __syncthreads();
    int local = 0;
    for (int i = threadIdx.x; i < n; i += THREADS) {
        unsigned ex = (x[i] >> 7) & 0xFF;
        if (ex == 0xFF || ex >= 134 || (ex > 0 && ex <= 100)) local++;
    }
    atomicAdd(&cnt, local);
    __syncthreads();
    if (threadIdx.x == 0) *flag = (cnt * 8 > n) ? 0 : 1;  // 1 = bf16
}

// ---------------- weight conversion to fp32 ----------------
struct ConvArgs {
    const void* src[21];
    float* dst[21];
    int prefix[22];
};

__global__ void convert_kernel(ConvArgs a, const int* __restrict__ flag, int total) {
    int i = blockIdx.x * THREADS + threadIdx.x;
    if (i >= total) return;
    bool isbf = (*flag != 0);
    int lo = 0;
    while (i >= a.prefix[lo + 1]) ++lo;
    int off = i - a.prefix[lo];
    float v;
    if (isbf) v = b2f(((const unsigned short*)a.src[lo])[off]);
    else v = ((const float*)a.src[lo])[off];
    a.dst[lo][off] = v;
}

// x -> bf16 [Npad,128], pad rows zero
__global__ void xconv_kernel(const void* __restrict__ xin, const int* __restrict__ flag,
                             unsigned short* __restrict__ xb, int N, int Npad) {
    int i = blockIdx.x * THREADS + threadIdx.x;
    if (i >= Npad * 128) return;
    if (i < N * 128) {
        if (*flag) xb[i] = ((const unsigned short*)xin)[i];
        else xb[i] = f2b(((const float*)xin)[i]);
    } else xb[i] = 0;
}

// W [128,cols] fp32 -> bf16 fragment-order for MFMA B-operand
// out[((t*4+ks)*64 + lane)*8 + j] = W[ks*32 + (lane>>4)*8 + j][t*16 + (lane&15)]
__global__ void wtf_kernel(const float* __restrict__ W, int cols, int colt,
                           unsigned short* __restrict__ out) {
    int id = blockIdx.x * THREADS + threadIdx.x;
    if (id >= colt * 256) return;
    int t = id >> 8, ks = (id >> 6) & 3, l = id & 63;
    int q = l >> 4, n = l & 15;
    int c = t * 16 + n;
#pragma unroll
    for (int j = 0; j < 8; ++j) {
        int k = ks * 32 + q * 8 + j;
        float v = (c < cols) ? W[k * cols + c] : 0.f;
        out[id * 8 + j] = f2b(v);
    }
}

// ---------------- CSR build ----------------
__global__ void count_kernel(const int* __restrict__ ei, int* __restrict__ deg, int E, int N) {
    int e = blockIdx.x * THREADS + threadIdx.x;
    if (e >= E + N) return;
    int d = (e < E) ? ei[E + e] : (e - E);
    atomicAdd(&deg[d], 1);
}

__global__ __launch_bounds__(1024) void scan_kernel(const int* __restrict__ deg,
                                                    int* __restrict__ row_ptr, int N) {
    __shared__ int sh[1024];
    int tid = threadIdx.x;
    int running = 0;
    for (int basei = 0; basei < N; basei += 8192) {
        int vals[8];
        int sum = 0;
        int b0 = basei + tid * 8;
#pragma unroll
        for (int i = 0; i < 8; i++) {
            int idx = b0 + i;
            int v = (idx < N) ? deg[idx] : 0;
            vals[i] = v;
            sum += v;
        }
        sh[tid] = sum;
        __syncthreads();
#pragma unroll
        for (int offv = 1; offv < 1024; offv <<= 1) {
            int t = (tid >= offv) ? sh[tid - offv] : 0;
            __syncthreads();
            sh[tid] += t;
            __syncthreads();
        }
        int excl = running + (tid ? sh[tid - 1] : 0);
        int tot = sh[1023];
#pragma unroll
        for (int i = 0; i < 8; i++) {
            int idx = b0 + i;
            excl += vals[i];
            if (idx < N) row_ptr[idx + 1] = excl;
        }
        running += tot;
        __syncthreads();
    }
    if (tid == 0) row_ptr[0] = 0;
}

__global__ void copy_kernel(const int* __restrict__ rp, int* __restrict__ pos, int N) {
    int n = blockIdx.x * THREADS + threadIdx.x;
    if (n < N) pos[n] = rp[n];
}

__global__ void scatter_kernel(const int* __restrict__ ei, int* __restrict__ pos,
                               int* __restrict__ csr, int E, int N) {
    int e = blockIdx.x * THREADS + threadIdx.x;
    if (e >= E + N) return;
    int s, d;
    if (e < E) { s = ei[e]; d = ei[E + e]; }
    else { s = e - E; d = s; }
    int p = atomicAdd(&pos[d], 1);
    csr[p] = s;
}

// ---------------- MFMA GEMM: [Npad,128]bf16 @ [128,cols]bf16 ----------------
// Block = 256 thr (4 waves), 64 rows/block, wave = 16 rows x cols.
// W in LDS fragment-order (conflict-free ds_read_b128); A frags direct from global.
__device__ inline void stv(float* p, float v) { *p = v; }
__device__ inline void stv(unsigned short* p, float v) { *p = f2b(v); }

template <int COLT, int HEADS, bool ES, typename OT>
__global__ __launch_bounds__(256) void gemm_mfma(
    const unsigned short* __restrict__ A, const unsigned short* __restrict__ Wg,
    const float* __restrict__ as_f, const float* __restrict__ ad_f,
    OT* __restrict__ out, int ldc, int cols,
    float* __restrict__ es, float* __restrict__ ed, int N) {
    __shared__ __align__(16) unsigned short Wls[COLT * 2048];
    int tid = threadIdx.x;
    {
        const float4* src = (const float4*)Wg;
        float4* dst = (float4*)Wls;
#pragma unroll
        for (int i = 0; i < COLT; ++i) dst[tid + i * 256] = src[tid + i * 256];
    }
    __syncthreads();
    int w = tid >> 6, lane = tid & 63;
    int n = lane & 15, q = lane >> 4;
    int row0 = blockIdx.x * 64 + w * 16;
    f32x4 acc[COLT];
#pragma unroll
    for (int t = 0; t < COLT; ++t) acc[t] = (f32x4){0.f, 0.f, 0.f, 0.f};
    const unsigned short* arow = A + (size_t)(row0 + n) * 128;
#pragma unroll
    for (int ks = 0; ks < 4; ++ks) {
        bfrag a = *reinterpret_cast<const bfrag*>(arow + ks * 32 + q * 8);
#pragma unroll
        for (int t = 0; t < COLT; ++t) {
            bfrag b = *reinterpret_cast<const bfrag*>(&Wls[((t * 4 + ks) * 64 + lane) * 8]);
            acc[t] = __builtin_amdgcn_mfma_f32_16x16x32_bf16(a, b, acc[t], 0, 0, 0);
        }
    }
    if (ES) {
        float asv[COLT], adv[COLT];
#pragma unroll
        for (int t = 0; t < COLT; ++t) {
            int c = t * 16 + n;
            asv[t] = (c < cols) ? as_f[c] : 0.f;
            adv[t] = (c < cols) ? ad_f[c] : 0.f;
        }
#pragma unroll
        for (int r = 0; r < 4; ++r) {
            float pe[HEADS], pd[HEADS];
#pragma unroll
            for (int h = 0; h < HEADS; ++h) { pe[h] = 0.f; pd[h] = 0.f; }
#pragma unroll
            for (int t = 0; t < COLT; ++t) {
                int h = (HEADS == 4) ? (t >> 1) : 0;
                pe[h] = fmaf(acc[t][r], asv[t], pe[h]);
                pd[h] = fmaf(acc[t][r], adv[t], pd[h]);
            }
#pragma unroll
            for (int h = 0; h < HEADS; ++h) {
#pragma unroll
                for (int o = 1; o < 16; o <<= 1) {
                    pe[h] += __shfl_xor(pe[h], o, 64);
                    pd[h] += __shfl_xor(pd[h], o, 64);
                }
            }
            int row = row0 + q * 4 + r;
            if (n == 0 && row < N) {
#pragma unroll
                for (int h = 0; h < HEADS; ++h) {
                    es[(size_t)row * HEADS + h] = pe[h];
                    ed[(size_t)row * HEADS + h] = pd[h];
                }
            }
        }
    }
#pragma unroll
    for (int t = 0; t < COLT; ++t) {
        int col = t * 16 + n;
        if (col < cols) {
#pragma unroll
            for (int r = 0; r < 4; ++r) {
                int row = row0 + q * 4 + r;
                if (row < N) stv(&out[(size_t)row * ldc + col], acc[t][r]);
            }
        }
    }
}

// ---------------- aggregation layers 1-2: 1 wave/node, 4 heads, bf16 gather ----------------
__global__ __launch_bounds__(256) void agg128_kernel(
    const unsigned short* __restrict__ xwb, const float* __restrict__ es,
    const float* __restrict__ ed, const int* __restrict__ row_ptr,
    const int* __restrict__ csr, const float* __restrict__ bias,
    float* __restrict__ out, int N) {
    int w = threadIdx.x >> 6;
    int lane = threadIdx.x & 63;
    int node = blockIdx.x * 4 + w;
    if (node >= N) return;
    int h = lane >> 4;          // head for this lane's 2 channels
    int c0 = lane * 2;
    float edl = ed[node * 4 + h];
    int start = row_ptr[node], end = row_ptr[node + 1];
    float den = 0.f, a0 = 0.f, a1 = 0.f;
    for (int j = start; j < end; ++j) {
        int s = csr[j];
        float e = es[s * 4 + h] + edl;
        e = e > 0.f ? e : 0.2f * e;
        float wg = __expf(e);   // no max pass: |e| small, fp32 exp safe
        den += wg;
        unsigned u = *(const unsigned*)(xwb + (size_t)s * 128 + c0);
        a0 = fmaf(wg, __uint_as_float(u << 16), a0);
        a1 = fmaf(wg, __uint_as_float(u & 0xffff0000u), a1);
    }
    float inv = 1.0f / den;
    float2 o = make_float2(a0 * inv + bias[c0], a1 * inv + bias[c0 + 1]);
    *(float2*)(out + (size_t)node * 128 + c0) = o;
}

// ---------------- BN + residual + ELU ----------------
__global__ void pw1_kernel(const float* __restrict__ gout, const float* __restrict__ res,
                           const float* __restrict__ g, const float* __restrict__ be,
                           const float* __restrict__ mm, const float* __restrict__ vv,
                           float* __restrict__ h1, unsigned short* __restrict__ h1b,
                           int N, int Npad) {
    int i = blockIdx.x * THREADS + threadIdx.x;
    if (i >= Npad * 128) return;
    if (i < N * 128) {
        int c = i & 127;
        float val = (gout[i] - mm[c]) * rsqrtf(vv[c] + 1e-5f) * g[c] + be[c] + res[i];
        val = val > 0.f ? val : expm1f(val);
        h1[i] = val;
        h1b[i] = f2b(val);
    } else h1b[i] = 0;
}

__global__ void pw2_kernel(const float* __restrict__ gout, const float* __restrict__ res,
                           const float* __restrict__ g, const float* __restrict__ be,
                           const float* __restrict__ mm, const float* __restrict__ vv,
                           unsigned short* __restrict__ h2b, int N, int Npad) {
    int i = blockIdx.x * THREADS + threadIdx.x;
    if (i >= Npad * 128) return;
    if (i < N * 128) {
        int c = i & 127;
        float val = (gout[i] - mm[c]) * rsqrtf(vv[c] + 1e-5f) * g[c] + be[c] + res[i];
        val = val > 0.f ? val : expm1f(val);
        h2b[i] = f2b(val);
    } else h2b[i] = 0;
}

// ---------------- layer-3 aggregation: 1 wave/node, 40 cols, writes d_out ----------------
__global__ __launch_bounds__(256) void agg40_kernel(
    const unsigned short* __restrict__ xw3b, const float* __restrict__ es3,
    const float* __restrict__ ed3, const int* __restrict__ row_ptr,
    const int* __restrict__ csr, const float* __restrict__ b3,
    void* __restrict__ out, const int* __restrict__ flag, int N) {
    int w = threadIdx.x >> 6;
    int lane = threadIdx.x & 63;
    int node = blockIdx.x * 4 + w;
    if (node >= N) return;
    float edl = ed3[node];
    int start = row_ptr[node], end = row_ptr[node + 1];
    int c = lane < 40 ? lane : 0;
    float den = 0.f, acc = 0.f;
    for (int j = start; j < end; ++j) {
        int s = csr[j];
        float e = es3[s] + edl;
        e = e > 0.f ? e : 0.2f * e;
        float wg = __expf(e);
        den += wg;
        acc = fmaf(wg, b2f(xw3b[(size_t)s * 40 + c]), acc);
    }
    if (lane < 40) {
        float v = acc / den + b3[lane];
        if (*flag)
            ((__hip_bfloat16*)out)[(size_t)node * 40 + lane] = __float2bfloat16(v);
        else
            ((float*)out)[(size_t)node * 40 + lane] = v;
    }
}

extern "C" void kernel_launch(void* const* d_in, const int* in_sizes, int n_in,
                              void* d_out, int out_size, void* d_ws, size_t ws_size,
                              hipStream_t stream) {
    (void)n_in; (void)out_size; (void)ws_size;
    const int N = in_sizes[0] / 128;
    const int E = in_sizes[1] / 2;
    const int EPN = E + N;
    const int Npad = (N + 127) & ~127;
    char* base = (char*)d_ws;
    size_t off = 0;
    auto alloc = [&](size_t bytes) -> char* {
        char* p = base + off;
        off = (off + bytes + 255) & ~(size_t)255;
        return p;
    };
    int* flag = (int*)alloc(4);
    int* deg = (int*)alloc((size_t)N * 4);
    int* row_ptr = (int*)alloc((size_t)(N + 1) * 4);
    int* pos = (int*)alloc((size_t)N * 4);
    int* csr = (int*)alloc((size_t)EPN * 4);
    float* wc = (float*)alloc((size_t)56184 * 4);
    unsigned short* Wl1 = (unsigned short*)alloc(32768);
    unsigned short* Wl2 = (unsigned short*)alloc(32768);
    unsigned short* WlR = (unsigned short*)alloc(32768);
    unsigned short* Wl3 = (unsigned short*)alloc(12288);
    unsigned short* xb = (unsigned short*)alloc((size_t)Npad * 128 * 2);
    unsigned short* h1b = (unsigned short*)alloc((size_t)Npad * 128 * 2);
    unsigned short* xwb = (unsigned short*)alloc((size_t)Npad * 128 * 2);  // also xw3b
    float* h1 = (float*)alloc((size_t)N * 128 * 4);
    float* gout = (float*)alloc((size_t)N * 128 * 4);
    float* res = (float*)alloc((size_t)Npad * 128 * 4);  // fp32 residual; later h2b bf16
    float* es = (float*)alloc((size_t)N * 4 * 4);
    float* ed = (float*)alloc((size_t)N * 4 * 4);

    const int* ei = (const int*)d_in[1];

    // fp32 weight region (float offsets)
    float* W1 = wc;            float* AS1 = wc + 16384; float* AD1 = wc + 16512; float* B1 = wc + 16640;
    float* W2 = wc + 16768;    float* AS2 = wc + 33152; float* AD2 = wc + 33280; float* B2 = wc + 33408;
    float* W3 = wc + 33536;    float* AS3 = wc + 38656; float* AD3 = wc + 38696; float* B3 = wc + 38736;
    float* WR = wc + 38776;
    float* G1 = wc + 55160; float* BE1 = wc + 55288; float* M1 = wc + 55416; float* V1 = wc + 55544;
    float* G2 = wc + 55672; float* BE2 = wc + 55800; float* M2 = wc + 55928; float* V2 = wc + 56056;

    hipMemsetAsync(deg, 0, (size_t)N * 4, stream);
    detect_kernel<<<1, THREADS, 0, stream>>>((const unsigned short*)d_in[0], 4096, flag);

    ConvArgs ca;
    const int idxs[21] = {2, 3, 4, 5, 6, 7, 8, 9, 10, 11, 12, 13, 14, 15, 16, 17, 18, 19, 20, 21, 22};
    float* dsts[21] = {W1, AS1, AD1, B1, W2, AS2, AD2, B2, W3, AS3, AD3, B3, WR,
                       G1, BE1, M1, V1, G2, BE2, M2, V2};
    int p = 0;
    for (int t = 0; t < 21; t++) {
        ca.src[t] = d_in[idxs[t]];
        ca.dst[t] = dsts[t];
        ca.prefix[t] = p;
        p += in_sizes[idxs[t]];
    }
    ca.prefix[21] = p;
    convert_kernel<<<(p + THREADS - 1) / THREADS, THREADS, 0, stream>>>(ca, flag, p);

    xconv_kernel<<<(Npad * 128 + THREADS - 1) / THREADS, THREADS, 0, stream>>>(
        d_in[0], flag, xb, N, Npad);
    wtf_kernel<<<8, THREADS, 0, stream>>>(W1, 128, 8, Wl1);
    wtf_kernel<<<8, THREADS, 0, stream>>>(W2, 128, 8, Wl2);
    wtf_kernel<<<8, THREADS, 0, stream>>>(WR, 128, 8, WlR);
    wtf_kernel<<<3, THREADS, 0, stream>>>(W3, 40, 3, Wl3);

    count_kernel<<<(EPN + THREADS - 1) / THREADS, THREADS, 0, stream>>>(ei, deg, E, N);
    scan_kernel<<<1, 1024, 0, stream>>>(deg, row_ptr, N);
    copy_kernel<<<(N + THREADS - 1) / THREADS, THREADS, 0, stream>>>(row_ptr, pos, N);
    scatter_kernel<<<(EPN + THREADS - 1) / THREADS, THREADS, 0, stream>>>(ei, pos, csr, E, N);

    int gemmGrid = Npad / 64;
    int aggGrid = (N + 3) / 4;
    int pwGrid = (Npad * 128 + THREADS - 1) / THREADS;

    // layer 1
    gemm_mfma<8, 4, true, unsigned short><<<gemmGrid, 256, 0, stream>>>(
        xb, Wl1, AS1, AD1, xwb, 128, 128, es, ed, N);
    agg128_kernel<<<aggGrid, 256, 0, stream>>>(xwb, es, ed, row_ptr, csr, B1, gout, N);
    gemm_mfma<8, 1, false, float><<<gemmGrid, 256, 0, stream>>>(
        xb, WlR, nullptr, nullptr, res, 128, 128, nullptr, nullptr, N);
    pw1_kernel<<<pwGrid, THREADS, 0, stream>>>(gout, res, G1, BE1, M1, V1, h1, h1b, N, Npad);
    // layer 2
    gemm_mfma<8, 4, true, unsigned short><<<gemmGrid, 256, 0, stream>>>(
        h1b, Wl2, AS2, AD2, xwb, 128, 128, es, ed, N);
    agg128_kernel<<<aggGrid, 256, 0, stream>>>(xwb, es, ed, row_ptr, csr, B2, gout, N);
    unsigned short* h2b = (unsigned short*)res;
    pw2_kernel<<<pwGrid, THREADS, 0, stream>>>(gout, h1, G2, BE2, M2, V2, h2b, N, Npad);
    // layer 3
    unsigned short* xw3b = xwb;
    gemm_mfma<3, 1, true, unsigned short><<<gemmGrid, 256, 0, stream>>>(
        h2b, Wl3, AS3, AD3, xw3b, 40, 40, es, ed, N);
    agg40_kernel<<<aggGrid, 256, 0, stream>>>(xw3b, es, ed, row_ptr, csr, B3, d_out, flag, N);
}

// Round 3
// 372.381 us; speedup vs baseline: 2.1509x; 1.2525x over previous
//
#include <hip/hip_runtime.h>
#include <hip/hip_bf16.h>

#define THREADS 256

typedef __attribute__((ext_vector_type(8))) short bfrag;     // 8 bf16 = 4 VGPR
typedef __attribute__((ext_vector_type(4))) float f32x4;     // MFMA accumulator

__device__ inline unsigned short f2b(float v) {
    __hip_bfloat16 b = __float2bfloat16(v);
    return *reinterpret_cast<unsigned short*>(&b);
}
__device__ inline float b2f(unsigned short u) {
    return __uint_as_float(((unsigned)u) << 16);
}

// ---------------- dtype detection (bf16 vs fp32 inputs) ----------------
__global__ void detect_kernel(const unsigned short* __restrict__ x, int n, int* flag) {
    __shared__ int cnt;
    if (threadIdx.x == 0) cnt = 0;
    __syncthreads();
    int local = 0;
    for (int i = threadIdx.x; i < n; i += THREADS) {
        unsigned ex = (x[i] >> 7) & 0xFF;
        if (ex == 0xFF || ex >= 134 || (ex > 0 && ex <= 100)) local++;
    }
    atomicAdd(&cnt, local);
    __syncthreads();
    if (threadIdx.x == 0) *flag = (cnt * 8 > n) ? 0 : 1;  // 1 = bf16
}

// ---------------- weight conversion to fp32 ----------------
struct ConvArgs {
    const void* src[21];
    float* dst[21];
    int prefix[22];
};

__global__ void convert_kernel(ConvArgs a, const int* __restrict__ flag, int total) {
    int i = blockIdx.x * THREADS + threadIdx.x;
    if (i >= total) return;
    bool isbf = (*flag != 0);
    int lo = 0;
    while (i >= a.prefix[lo + 1]) ++lo;
    int off = i - a.prefix[lo];
    float v;
    if (isbf) v = b2f(((const unsigned short*)a.src[lo])[off]);
    else v = ((const float*)a.src[lo])[off];
    a.dst[lo][off] = v;
}

// x fp32 -> bf16 (only needed when inputs are fp32; bf16 path reads raw)
__global__ void xconv_kernel(const float* __restrict__ xin, const int* __restrict__ flag,
                             unsigned short* __restrict__ xb, int total) {
    if (*flag) return;
    int i = blockIdx.x * THREADS + threadIdx.x;
    if (i >= total) return;
    xb[i] = f2b(xin[i]);
}

// W [128,cols] fp32 -> bf16 fragment-order for MFMA B-operand (all 4 weights, one launch)
// out[((t*4+ks)*64 + lane)*8 + j] = W[ks*32 + (lane>>4)*8 + j][t*16 + (lane&15)]
__global__ void wtf_all(const float* __restrict__ W1, const float* __restrict__ W2,
                        const float* __restrict__ WR, const float* __restrict__ W3,
                        unsigned short* __restrict__ o1, unsigned short* __restrict__ o2,
                        unsigned short* __restrict__ oR, unsigned short* __restrict__ o3) {
    int b = blockIdx.x;
    const float* W; unsigned short* o; int cols, tt;
    if (b < 8)       { W = W1; o = o1; cols = 128; tt = b; }
    else if (b < 16) { W = W2; o = o2; cols = 128; tt = b - 8; }
    else if (b < 24) { W = WR; o = oR; cols = 128; tt = b - 16; }
    else             { W = W3; o = o3; cols = 40;  tt = b - 24; }
    int id = tt * 256 + threadIdx.x;
    int t = id >> 8, ks = (id >> 6) & 3, l = id & 63;
    int q = l >> 4, n = l & 15;
    int c = t * 16 + n;
#pragma unroll
    for (int j = 0; j < 8; ++j) {
        int k = ks * 32 + q * 8 + j;
        float v = (c < cols) ? W[k * cols + c] : 0.f;
        o[id * 8 + j] = f2b(v);
    }
}

// BN fold: sc = g*rsqrt(v+eps); sh = be - m*sc + bias*sc  (bias folded in)
__global__ void bnprep_kernel(const float* __restrict__ g1, const float* __restrict__ be1,
                              const float* __restrict__ m1, const float* __restrict__ v1,
                              const float* __restrict__ b1, const float* __restrict__ g2,
                              const float* __restrict__ be2, const float* __restrict__ m2,
                              const float* __restrict__ v2, const float* __restrict__ b2,
                              float* __restrict__ sc1, float* __restrict__ sh1,
                              float* __restrict__ sc2, float* __restrict__ sh2) {
    int c = threadIdx.x;
    if (c < 128) {
        float s = g1[c] * rsqrtf(v1[c] + 1e-5f);
        sc1[c] = s;
        sh1[c] = be1[c] - m1[c] * s + b1[c] * s;
    } else {
        int d = c - 128;
        float s = g2[d] * rsqrtf(v2[d] + 1e-5f);
        sc2[d] = s;
        sh2[d] = be2[d] - m2[d] * s + b2[d] * s;
    }
}

// ---------------- CSR build ----------------
__global__ void count_kernel(const int* __restrict__ ei, int* __restrict__ deg, int E, int N) {
    int e = blockIdx.x * THREADS + threadIdx.x;
    if (e >= E + N) return;
    int d = (e < E) ? ei[E + e] : (e - E);
    atomicAdd(&deg[d], 1);
}

// shfl-scan: 2 barriers/chunk (old Hillis-Steele had 20 -> was 56us barrier-bound)
__global__ __launch_bounds__(1024) void scan_kernel(const int* __restrict__ deg,
                                                    int* __restrict__ row_ptr,
                                                    int* __restrict__ pos, int N) {
    __shared__ int wsum[16];
    int tid = threadIdx.x, lane = tid & 63, wv = tid >> 6;
    int carry = 0;
    for (int base0 = 0; base0 < N; base0 += 8192) {
        int b0 = base0 + tid * 8;
        int vals[8];
        int sum = 0;
#pragma unroll
        for (int i = 0; i < 8; ++i) {
            int idx = b0 + i;
            int v = (idx < N) ? deg[idx] : 0;
            vals[i] = v;
            sum += v;
        }
        int sc = sum;
#pragma unroll
        for (int o = 1; o < 64; o <<= 1) {
            int t = __shfl_up(sc, o, 64);
            if (lane >= o) sc += t;
        }
        if (lane == 63) wsum[wv] = sc;
        __syncthreads();
        int wexcl = 0, total = 0;
#pragma unroll
        for (int k = 0; k < 16; ++k) {
            int v = wsum[k];
            if (k < wv) wexcl += v;
            total += v;
        }
        int excl = carry + wexcl + sc - sum;
#pragma unroll
        for (int i = 0; i < 8; ++i) {
            int idx = b0 + i;
            if (idx < N) pos[idx] = excl;
            excl += vals[i];
            if (idx < N) row_ptr[idx + 1] = excl;
        }
        carry += total;
        __syncthreads();
    }
    if (tid == 0) row_ptr[0] = 0;
}

__global__ void scatter_kernel(const int* __restrict__ ei, int* __restrict__ pos,
                               int* __restrict__ csr, int E, int N) {
    int e = blockIdx.x * THREADS + threadIdx.x;
    if (e >= E + N) return;
    int s, d;
    if (e < E) { s = ei[e]; d = ei[E + e]; }
    else { s = e - E; d = s; }
    int p = atomicAdd(&pos[d], 1);
    csr[p] = s;
}

// ---------------- MFMA GEMM: [N,128]bf16 @ [128,cols]bf16 ----------------
template <int COLT, int HEADS, bool ES, typename OT>
__global__ __launch_bounds__(256) void gemm_mfma(
    const unsigned short* __restrict__ A, const unsigned short* __restrict__ Wg,
    const float* __restrict__ as_f, const float* __restrict__ ad_f,
    OT* __restrict__ out, int ldc, int cols,
    float* __restrict__ es, float* __restrict__ ed, int N) {
    __shared__ __align__(16) unsigned short Wls[COLT * 2048];
    int tid = threadIdx.x;
    {
        const float4* src = (const float4*)Wg;
        float4* dst = (float4*)Wls;
#pragma unroll
        for (int i = 0; i < COLT; ++i) dst[tid + i * 256] = src[tid + i * 256];
    }
    __syncthreads();
    int w = tid >> 6, lane = tid & 63;
    int n = lane & 15, q = lane >> 4;
    int row0 = blockIdx.x * 64 + w * 16;
    int ar = row0 + n; ar = ar < N ? ar : N - 1;   // clamp: OOB rows harmless (row-independent)
    f32x4 acc[COLT];
#pragma unroll
    for (int t = 0; t < COLT; ++t) acc[t] = (f32x4){0.f, 0.f, 0.f, 0.f};
    const unsigned short* arow = A + (size_t)ar * 128;
#pragma unroll
    for (int ks = 0; ks < 4; ++ks) {
        bfrag a = *reinterpret_cast<const bfrag*>(arow + ks * 32 + q * 8);
#pragma unroll
        for (int t = 0; t < COLT; ++t) {
            bfrag b = *reinterpret_cast<const bfrag*>(&Wls[((t * 4 + ks) * 64 + lane) * 8]);
            acc[t] = __builtin_amdgcn_mfma_f32_16x16x32_bf16(a, b, acc[t], 0, 0, 0);
        }
    }
    if (ES) {
        float asv[COLT], adv[COLT];
#pragma unroll
        for (int t = 0; t < COLT; ++t) {
            int c = t * 16 + n;
            asv[t] = (c < cols) ? as_f[c] : 0.f;
            adv[t] = (c < cols) ? ad_f[c] : 0.f;
        }
#pragma unroll
        for (int r = 0; r < 4; ++r) {
            float pe[HEADS], pd[HEADS];
#pragma unroll
            for (int h = 0; h < HEADS; ++h) { pe[h] = 0.f; pd[h] = 0.f; }
#pragma unroll
            for (int t = 0; t < COLT; ++t) {
                int h = (HEADS == 4) ? (t >> 1) : 0;
                pe[h] = fmaf(acc[t][r], asv[t], pe[h]);
                pd[h] = fmaf(acc[t][r], adv[t], pd[h]);
            }
#pragma unroll
            for (int h = 0; h < HEADS; ++h) {
#pragma unroll
                for (int o = 1; o < 16; o <<= 1) {
                    pe[h] += __shfl_xor(pe[h], o, 64);
                    pd[h] += __shfl_xor(pd[h], o, 64);
                }
            }
            int row = row0 + q * 4 + r;
            if (n == 0 && row < N) {
#pragma unroll
                for (int h = 0; h < HEADS; ++h) {
                    es[(size_t)row * HEADS + h] = pe[h];
                    ed[(size_t)row * HEADS + h] = pd[h];
                }
            }
        }
    }
#pragma unroll
    for (int t = 0; t < COLT; ++t) {
        int col = t * 16 + n;
        if (col < cols) {
#pragma unroll
            for (int r = 0; r < 4; ++r) {
                int row = row0 + q * 4 + r;
                if (row < N) {
                    float v = acc[t][r];
                    out[(size_t)row * ldc + col] = (sizeof(OT) == 2) ? (OT)f2b(v) : (OT)v;
                }
            }
        }
    }
}

// W1 + Wres in one pass (A read once): tiles 0..7 -> xwb bf16 + es/ed; 8..15 -> res fp32
__global__ __launch_bounds__(256) void gemm_dual(
    const unsigned short* __restrict__ Araw, const unsigned short* __restrict__ Acvt,
    const int* __restrict__ flag,
    const unsigned short* __restrict__ Wg1, const unsigned short* __restrict__ WgR,
    const float* __restrict__ as_f, const float* __restrict__ ad_f,
    unsigned short* __restrict__ xwb, float* __restrict__ resf,
    float* __restrict__ es, float* __restrict__ ed, int N) {
    __shared__ __align__(16) unsigned short Wls[16 * 2048];
    int tid = threadIdx.x;
    {
        const float4* s1 = (const float4*)Wg1;
        const float4* s2 = (const float4*)WgR;
        float4* dst = (float4*)Wls;
#pragma unroll
        for (int i = 0; i < 8; ++i) dst[tid + i * 256] = s1[tid + i * 256];
#pragma unroll
        for (int i = 0; i < 8; ++i) dst[2048 + tid + i * 256] = s2[tid + i * 256];
    }
    const unsigned short* A = (*flag) ? Araw : Acvt;
    __syncthreads();
    int w = tid >> 6, lane = tid & 63;
    int n = lane & 15, q = lane >> 4;
    int row0 = blockIdx.x * 64 + w * 16;
    int ar = row0 + n; ar = ar < N ? ar : N - 1;
    f32x4 acc[16];
#pragma unroll
    for (int t = 0; t < 16; ++t) acc[t] = (f32x4){0.f, 0.f, 0.f, 0.f};
    const unsigned short* arow = A + (size_t)ar * 128;
#pragma unroll
    for (int ks = 0; ks < 4; ++ks) {
        bfrag a = *reinterpret_cast<const bfrag*>(arow + ks * 32 + q * 8);
#pragma unroll
        for (int t = 0; t < 8; ++t) {
            bfrag b = *reinterpret_cast<const bfrag*>(&Wls[((t * 4 + ks) * 64 + lane) * 8]);
            acc[t] = __builtin_amdgcn_mfma_f32_16x16x32_bf16(a, b, acc[t], 0, 0, 0);
        }
#pragma unroll
        for (int t = 0; t < 8; ++t) {
            bfrag b = *reinterpret_cast<const bfrag*>(&Wls[16384 + ((t * 4 + ks) * 64 + lane) * 8]);
            acc[8 + t] = __builtin_amdgcn_mfma_f32_16x16x32_bf16(a, b, acc[8 + t], 0, 0, 0);
        }
    }
    float asv[8], adv[8];
#pragma unroll
    for (int t = 0; t < 8; ++t) {
        int c = t * 16 + n;
        asv[t] = as_f[c];
        adv[t] = ad_f[c];
    }
#pragma unroll
    for (int r = 0; r < 4; ++r) {
        float pe[4] = {0.f, 0.f, 0.f, 0.f}, pd[4] = {0.f, 0.f, 0.f, 0.f};
#pragma unroll
        for (int t = 0; t < 8; ++t) {
            int h = t >> 1;
            pe[h] = fmaf(acc[t][r], asv[t], pe[h]);
            pd[h] = fmaf(acc[t][r], adv[t], pd[h]);
        }
#pragma unroll
        for (int h = 0; h < 4; ++h) {
#pragma unroll
            for (int o = 1; o < 16; o <<= 1) {
                pe[h] += __shfl_xor(pe[h], o, 64);
                pd[h] += __shfl_xor(pd[h], o, 64);
            }
        }
        int row = row0 + q * 4 + r;
        if (n == 0 && row < N) {
#pragma unroll
            for (int h = 0; h < 4; ++h) {
                es[(size_t)row * 4 + h] = pe[h];
                ed[(size_t)row * 4 + h] = pd[h];
            }
        }
    }
#pragma unroll
    for (int t = 0; t < 8; ++t) {
        int col = t * 16 + n;
#pragma unroll
        for (int r = 0; r < 4; ++r) {
            int row = row0 + q * 4 + r;
            if (row < N) {
                xwb[(size_t)row * 128 + col] = f2b(acc[t][r]);
                resf[(size_t)row * 128 + col] = acc[8 + t][r];
            }
        }
    }
}

// ---------------- agg layers 1-2 + fused BN/bias/residual/ELU ----------------
// wave/node; 16-edge chunks: 1 coalesced index load, lane-parallel weights,
// shfl-broadcast in gather loop (no dependent load chain), 4-unrolled MLP.
template <bool WF32>
__global__ __launch_bounds__(256) void agg128_fused(
    const unsigned short* __restrict__ xwb, const float* __restrict__ es,
    const float* __restrict__ ed, const int* __restrict__ row_ptr,
    const int* __restrict__ csr, const float* __restrict__ bnsc,
    const float* __restrict__ bnsh, const float* __restrict__ res,
    float* __restrict__ outf, unsigned short* __restrict__ outb, int N) {
    int w = threadIdx.x >> 6, lane = threadIdx.x & 63;
    int node = blockIdx.x * 4 + w;
    if (node >= N) return;
    int h = lane >> 4;
    int i16 = lane & 15;
    int base = lane & 48;
    int c0 = lane * 2;
    float edl = ed[node * 4 + h];
    int start = row_ptr[node], end = row_ptr[node + 1];
    float den = 0.f, a0 = 0.f, a1 = 0.f;
    for (int jb = start; jb < end; jb += 16) {
        int cnt = end - jb; cnt = cnt < 16 ? cnt : 16;
        int sv = csr[jb + (i16 < cnt ? i16 : 0)];
        float wgl = 0.f;
        if (i16 < cnt) {
            float e = es[sv * 4 + h] + edl;
            e = e > 0.f ? e : 0.2f * e;
            wgl = __expf(e);
        }
        float d = wgl;
        d += __shfl_xor(d, 1, 64);
        d += __shfl_xor(d, 2, 64);
        d += __shfl_xor(d, 4, 64);
        d += __shfl_xor(d, 8, 64);
        den += d;
        for (int j4 = 0; j4 < cnt; j4 += 4) {
#pragma unroll
            for (int u = 0; u < 4; ++u) {
                int j = j4 + u;
                int s = __shfl(sv, j, 64);
                float wg = __shfl(wgl, base + j, 64);   // 0 for padded slots
                unsigned uu = *(const unsigned*)(xwb + (size_t)s * 128 + c0);
                a0 = fmaf(wg, __uint_as_float(uu << 16), a0);
                a1 = fmaf(wg, __uint_as_float(uu & 0xffff0000u), a1);
            }
        }
    }
    float inv = 1.f / den;
    float2 sc = *(const float2*)(bnsc + c0);
    float2 sh = *(const float2*)(bnsh + c0);
    float2 rr = *(const float2*)(res + (size_t)node * 128 + c0);
    float v0 = fmaf(a0 * inv, sc.x, sh.x) + rr.x;
    float v1 = fmaf(a1 * inv, sc.y, sh.y) + rr.y;
    v0 = v0 > 0.f ? v0 : expm1f(v0);
    v1 = v1 > 0.f ? v1 : expm1f(v1);
    if (WF32) *(float2*)(outf + (size_t)node * 128 + c0) = make_float2(v0, v1);
    unsigned pk = (unsigned)f2b(v0) | ((unsigned)f2b(v1) << 16);
    *(unsigned*)(outb + (size_t)node * 128 + c0) = pk;
}

// ---------------- layer-3 agg (H=1, 40ch): 3 edges in flight across lane groups ----------------
__global__ __launch_bounds__(256) void agg40_kernel(
    const unsigned short* __restrict__ xw3b, const float* __restrict__ es3,
    const float* __restrict__ ed3, const int* __restrict__ row_ptr,
    const int* __restrict__ csr, const float* __restrict__ b3,
    void* __restrict__ out, const int* __restrict__ flag, int N) {
    int w = threadIdx.x >> 6, lane = threadIdx.x & 63;
    int node = blockIdx.x * 4 + w;
    if (node >= N) return;
    int i16 = lane & 15;
    int g = lane >= 40 ? 2 : (lane >= 20 ? 1 : 0);
    int cp = lane - g * 20;
    int c0 = cp * 2; c0 = c0 > 38 ? 38 : c0;
    float edl = ed3[node];
    int start = row_ptr[node], end = row_ptr[node + 1];
    float den = 0.f, a0 = 0.f, a1 = 0.f;
    for (int jb = start; jb < end; jb += 16) {
        int cnt = end - jb; cnt = cnt < 16 ? cnt : 16;
        int sv = csr[jb + (i16 < cnt ? i16 : 0)];
        float wgl = 0.f;
        if (i16 < cnt) {
            float e = es3[sv] + edl;
            e = e > 0.f ? e : 0.2f * e;
            wgl = __expf(e);
        }
        float d = wgl;
        d += __shfl_xor(d, 1, 64);
        d += __shfl_xor(d, 2, 64);
        d += __shfl_xor(d, 4, 64);
        d += __shfl_xor(d, 8, 64);
        den += d;
        for (int j = 0; j < cnt; j += 3) {
            int slot = j + g;
            int sl = slot < 15 ? slot : 15;
            int s = __shfl(sv, sl, 64);
            float wg = __shfl(wgl, sl, 64);
            if (slot >= cnt) wg = 0.f;
            unsigned uu = *(const unsigned*)(xw3b + (size_t)s * 40 + c0);
            a0 = fmaf(wg, __uint_as_float(uu << 16), a0);
            a1 = fmaf(wg, __uint_as_float(uu & 0xffff0000u), a1);
        }
    }
    float t0 = __shfl(a0, (lane + 20) & 63, 64);
    float t1 = __shfl(a0, (lane + 40) & 63, 64);
    float u0 = __shfl(a1, (lane + 20) & 63, 64);
    float u1 = __shfl(a1, (lane + 40) & 63, 64);
    a0 += t0 + t1;
    a1 += u0 + u1;
    if (lane < 20) {
        float inv = 1.f / den;
        float v0 = a0 * inv + b3[c0];
        float v1 = a1 * inv + b3[c0 + 1];
        size_t eoff = (size_t)node * 40 + c0;
        if (*flag) {
            unsigned pk = (unsigned)f2b(v0) | ((unsigned)f2b(v1) << 16);
            *(unsigned*)((unsigned short*)out + eoff) = pk;
        } else {
            *(float2*)((float*)out + eoff) = make_float2(v0, v1);
        }
    }
}

extern "C" void kernel_launch(void* const* d_in, const int* in_sizes, int n_in,
                              void* d_out, int out_size, void* d_ws, size_t ws_size,
                              hipStream_t stream) {
    (void)n_in; (void)out_size; (void)ws_size;
    const int N = in_sizes[0] / 128;
    const int E = in_sizes[1] / 2;
    const int EPN = E + N;
    char* base = (char*)d_ws;
    size_t off = 0;
    auto alloc = [&](size_t bytes) -> char* {
        char* p = base + off;
        off = (off + bytes + 255) & ~(size_t)255;
        return p;
    };
    int* flag = (int*)alloc(4);
    int* deg = (int*)alloc((size_t)N * 4);
    int* row_ptr = (int*)alloc((size_t)(N + 1) * 4);
    int* pos = (int*)alloc((size_t)N * 4);
    int* csr = (int*)alloc((size_t)EPN * 4);
    float* wc = (float*)alloc((size_t)56184 * 4);
    float* bnsc1 = (float*)alloc(512); float* bnsh1 = (float*)alloc(512);
    float* bnsc2 = (float*)alloc(512); float* bnsh2 = (float*)alloc(512);
    unsigned short* Wl1 = (unsigned short*)alloc(32768);
    unsigned short* Wl2 = (unsigned short*)alloc(32768);
    unsigned short* WlR = (unsigned short*)alloc(32768);
    unsigned short* Wl3 = (unsigned short*)alloc(12288);
    unsigned short* xb = (unsigned short*)alloc((size_t)N * 128 * 2);
    unsigned short* xwb = (unsigned short*)alloc((size_t)N * 128 * 2);  // also xw3b
    unsigned short* h1b = (unsigned short*)alloc((size_t)N * 128 * 2);
    float* h1 = (float*)alloc((size_t)N * 128 * 4);
    float* resf = (float*)alloc((size_t)N * 128 * 4);  // layer1 residual; later h2b bf16
    float* es = (float*)alloc((size_t)N * 4 * 4);
    float* ed = (float*)alloc((size_t)N * 4 * 4);

    const int* ei = (const int*)d_in[1];

    float* W1 = wc;            float* AS1 = wc + 16384; float* AD1 = wc + 16512; float* B1 = wc + 16640;
    float* W2 = wc + 16768;    float* AS2 = wc + 33152; float* AD2 = wc + 33280; float* B2 = wc + 33408;
    float* W3 = wc + 33536;    float* AS3 = wc + 38656; float* AD3 = wc + 38696; float* B3 = wc + 38736;
    float* WR = wc + 38776;
    float* G1 = wc + 55160; float* BE1 = wc + 55288; float* M1 = wc + 55416; float* V1 = wc + 55544;
    float* G2 = wc + 55672; float* BE2 = wc + 55800; float* M2 = wc + 55928; float* V2 = wc + 56056;

    hipMemsetAsync(deg, 0, (size_t)N * 4, stream);
    detect_kernel<<<1, THREADS, 0, stream>>>((const unsigned short*)d_in[0], 4096, flag);

    ConvArgs ca;
    const int idxs[21] = {2, 3, 4, 5, 6, 7, 8, 9, 10, 11, 12, 13, 14, 15, 16, 17, 18, 19, 20, 21, 22};
    float* dsts[21] = {W1, AS1, AD1, B1, W2, AS2, AD2, B2, W3, AS3, AD3, B3, WR,
                       G1, BE1, M1, V1, G2, BE2, M2, V2};
    int p = 0;
    for (int t = 0; t < 21; t++) {
        ca.src[t] = d_in[idxs[t]];
        ca.dst[t] = dsts[t];
        ca.prefix[t] = p;
        p += in_sizes[idxs[t]];
    }
    ca.prefix[21] = p;
    convert_kernel<<<(p + THREADS - 1) / THREADS, THREADS, 0, stream>>>(ca, flag, p);

    xconv_kernel<<<(N * 128 + THREADS - 1) / THREADS, THREADS, 0, stream>>>(
        (const float*)d_in[0], flag, xb, N * 128);
    wtf_all<<<27, THREADS, 0, stream>>>(W1, W2, WR, W3, Wl1, Wl2, WlR, Wl3);
    bnprep_kernel<<<1, THREADS, 0, stream>>>(G1, BE1, M1, V1, B1, G2, BE2, M2, V2, B2,
                                             bnsc1, bnsh1, bnsc2, bnsh2);

    count_kernel<<<(EPN + THREADS - 1) / THREADS, THREADS, 0, stream>>>(ei, deg, E, N);
    scan_kernel<<<1, 1024, 0, stream>>>(deg, row_ptr, pos, N);
    scatter_kernel<<<(EPN + THREADS - 1) / THREADS, THREADS, 0, stream>>>(ei, pos, csr, E, N);

    int gemmGrid = (N + 63) / 64;
    int aggGrid = (N + 3) / 4;

    // layer 1 (W1 + Wres fused GEMM; BN/bias/res/ELU fused into agg epilogue)
    gemm_dual<<<gemmGrid, 256, 0, stream>>>((const unsigned short*)d_in[0], xb, flag,
                                            Wl1, WlR, AS1, AD1, xwb, resf, es, ed, N);
    agg128_fused<true><<<aggGrid, 256, 0, stream>>>(xwb, es, ed, row_ptr, csr,
                                                    bnsc1, bnsh1, resf, h1, h1b, N);
    // layer 2
    gemm_mfma<8, 4, true, unsigned short><<<gemmGrid, 256, 0, stream>>>(
        h1b, Wl2, AS2, AD2, xwb, 128, 128, es, ed, N);
    unsigned short* h2b = (unsigned short*)resf;
    agg128_fused<false><<<aggGrid, 256, 0, stream>>>(xwb, es, ed, row_ptr, csr,
                                                     bnsc2, bnsh2, h1, nullptr, h2b, N);
    // layer 3
    gemm_mfma<3, 1, true, unsigned short><<<gemmGrid, 256, 0, stream>>>(
        h2b, Wl3, AS3, AD3, xwb, 40, 40, es, ed, N);
    agg40_kernel<<<aggGrid, 256, 0, stream>>>(xwb, es, ed, row_ptr, csr, B3, d_out, flag, N);
}

// Round 4
// 309.094 us; speedup vs baseline: 2.5914x; 1.2047x over previous
//
#include <hip/hip_runtime.h>
#include <hip/hip_bf16.h>

#define THREADS 256

typedef __attribute__((ext_vector_type(8))) short bfrag;     // 8 bf16 = 4 VGPR
typedef __attribute__((ext_vector_type(4))) float f32x4;     // MFMA accumulator

__device__ inline unsigned short f2b(float v) {
    __hip_bfloat16 b = __float2bfloat16(v);
    return *reinterpret_cast<unsigned short*>(&b);
}
__device__ inline float b2f(unsigned short u) {
    return __uint_as_float(((unsigned)u) << 16);
}

// ---------------- dtype detection (bf16 vs fp32 inputs) ----------------
__global__ void detect_kernel(const unsigned short* __restrict__ x, int n, int* flag) {
    __shared__ int cnt;
    if (threadIdx.x == 0) cnt = 0;
    __syncthreads();
    int local = 0;
    for (int i = threadIdx.x; i < n; i += THREADS) {
        unsigned ex = (x[i] >> 7) & 0xFF;
        if (ex == 0xFF || ex >= 134 || (ex > 0 && ex <= 100)) local++;
    }
    atomicAdd(&cnt, local);
    __syncthreads();
    if (threadIdx.x == 0) *flag = (cnt * 8 > n) ? 0 : 1;  // 1 = bf16
}

// ---------------- weight conversion to fp32 ----------------
struct ConvArgs {
    const void* src[21];
    float* dst[21];
    int prefix[22];
};

__global__ void convert_kernel(ConvArgs a, const int* __restrict__ flag, int total) {
    int i = blockIdx.x * THREADS + threadIdx.x;
    if (i >= total) return;
    bool isbf = (*flag != 0);
    int lo = 0;
    while (i >= a.prefix[lo + 1]) ++lo;
    int off = i - a.prefix[lo];
    float v;
    if (isbf) v = b2f(((const unsigned short*)a.src[lo])[off]);
    else v = ((const float*)a.src[lo])[off];
    a.dst[lo][off] = v;
}

// x fp32 -> bf16 (only needed when inputs are fp32; bf16 path reads raw)
__global__ void xconv_kernel(const float* __restrict__ xin, const int* __restrict__ flag,
                             unsigned short* __restrict__ xb, int total) {
    if (*flag) return;
    int i = blockIdx.x * THREADS + threadIdx.x;
    if (i >= total) return;
    xb[i] = f2b(xin[i]);
}

// W [128,cols] fp32 -> bf16 fragment-order for MFMA B-operand (all 4 weights, one launch)
__global__ void wtf_all(const float* __restrict__ W1, const float* __restrict__ W2,
                        const float* __restrict__ WR, const float* __restrict__ W3,
                        unsigned short* __restrict__ o1, unsigned short* __restrict__ o2,
                        unsigned short* __restrict__ oR, unsigned short* __restrict__ o3) {
    int b = blockIdx.x;
    const float* W; unsigned short* o; int cols, tt;
    if (b < 8)       { W = W1; o = o1; cols = 128; tt = b; }
    else if (b < 16) { W = W2; o = o2; cols = 128; tt = b - 8; }
    else if (b < 24) { W = WR; o = oR; cols = 128; tt = b - 16; }
    else             { W = W3; o = o3; cols = 40;  tt = b - 24; }
    int id = tt * 256 + threadIdx.x;
    int t = id >> 8, ks = (id >> 6) & 3, l = id & 63;
    int q = l >> 4, n = l & 15;
    int c = t * 16 + n;
#pragma unroll
    for (int j = 0; j < 8; ++j) {
        int k = ks * 32 + q * 8 + j;
        float v = (c < cols) ? W[k * cols + c] : 0.f;
        o[id * 8 + j] = f2b(v);
    }
}

// BN fold: sc = g*rsqrt(v+eps); sh = be - m*sc + bias*sc
__global__ void bnprep_kernel(const float* __restrict__ g1, const float* __restrict__ be1,
                              const float* __restrict__ m1, const float* __restrict__ v1,
                              const float* __restrict__ b1, const float* __restrict__ g2,
                              const float* __restrict__ be2, const float* __restrict__ m2,
                              const float* __restrict__ v2, const float* __restrict__ b2,
                              float* __restrict__ sc1, float* __restrict__ sh1,
                              float* __restrict__ sc2, float* __restrict__ sh2) {
    int c = threadIdx.x;
    if (c < 128) {
        float s = g1[c] * rsqrtf(v1[c] + 1e-5f);
        sc1[c] = s;
        sh1[c] = be1[c] - m1[c] * s + b1[c] * s;
    } else {
        int d = c - 128;
        float s = g2[d] * rsqrtf(v2[d] + 1e-5f);
        sc2[d] = s;
        sh2[d] = be2[d] - m2[d] * s + b2[d] * s;
    }
}

// ---------------- CSR build (parallel 3-stage scan; no single-block serial loop) ----------------
__global__ void count_kernel(const int* __restrict__ ei, int* __restrict__ deg, int E, int N) {
    int e = blockIdx.x * THREADS + threadIdx.x;
    if (e >= E + N) return;
    int d = (e < E) ? ei[E + e] : (e - E);
    atomicAdd(&deg[d], 1);
}

// stage 1: per-block (256 elems) degree sums
__global__ void bsum_kernel(const int* __restrict__ deg, int* __restrict__ bsum, int N) {
    int idx = blockIdx.x * 256 + threadIdx.x;
    int lane = threadIdx.x & 63, wv = threadIdx.x >> 6;
    int v = (idx < N) ? deg[idx] : 0;
#pragma unroll
    for (int o = 1; o < 64; o <<= 1) v += __shfl_xor(v, o, 64);
    __shared__ int ws[4];
    if (lane == 0) ws[wv] = v;
    __syncthreads();
    if (threadIdx.x == 0) bsum[blockIdx.x] = ws[0] + ws[1] + ws[2] + ws[3];
}

// stage 2: exclusive scan of block sums (nb <= 1024), one block
__global__ __launch_bounds__(1024) void bscan_kernel(const int* __restrict__ bsum,
                                                     int* __restrict__ boff, int nb) {
    __shared__ int ws[16];
    int tid = threadIdx.x, lane = tid & 63, wv = tid >> 6;
    int v = (tid < nb) ? bsum[tid] : 0;
    int sc = v;
#pragma unroll
    for (int o = 1; o < 64; o <<= 1) {
        int t = __shfl_up(sc, o, 64);
        if (lane >= o) sc += t;
    }
    if (lane == 63) ws[wv] = sc;
    __syncthreads();
    int add = 0;
#pragma unroll
    for (int k = 0; k < 16; ++k) add += (k < wv) ? ws[k] : 0;
    if (tid < nb) boff[tid] = add + sc - v;
}

// stage 3: local scan + block offset -> row_ptr, pos
__global__ void scanw_kernel(const int* __restrict__ deg, const int* __restrict__ boff,
                             int* __restrict__ row_ptr, int* __restrict__ pos, int N) {
    int idx = blockIdx.x * 256 + threadIdx.x;
    int lane = threadIdx.x & 63, wv = threadIdx.x >> 6;
    int v = (idx < N) ? deg[idx] : 0;
    int sc = v;
#pragma unroll
    for (int o = 1; o < 64; o <<= 1) {
        int t = __shfl_up(sc, o, 64);
        if (lane >= o) sc += t;
    }
    __shared__ int ws[4];
    if (lane == 63) ws[wv] = sc;
    __syncthreads();
    int add = boff[blockIdx.x];
#pragma unroll
    for (int k = 0; k < 4; ++k) add += (k < wv) ? ws[k] : 0;
    int excl = add + sc - v;
    if (idx < N) {
        pos[idx] = excl;
        row_ptr[idx + 1] = excl + v;
    }
    if (idx == 0) row_ptr[0] = 0;
}

__global__ void scatter_kernel(const int* __restrict__ ei, int* __restrict__ pos,
                               int* __restrict__ csr, int E, int N) {
    int e = blockIdx.x * THREADS + threadIdx.x;
    if (e >= E + N) return;
    int s, d;
    if (e < E) { s = ei[e]; d = ei[E + e]; }
    else { s = e - E; d = s; }
    int p = atomicAdd(&pos[d], 1);
    csr[p] = s;
}

// ---------------- MFMA GEMM: [N,128]bf16 @ [128,cols]bf16 ----------------
template <int COLT, int HEADS, bool ES, typename OT>
__global__ __launch_bounds__(256) void gemm_mfma(
    const unsigned short* __restrict__ A, const unsigned short* __restrict__ Wg,
    const float* __restrict__ as_f, const float* __restrict__ ad_f,
    OT* __restrict__ out, int ldc, int cols,
    float* __restrict__ es, float* __restrict__ ed, int N) {
    __shared__ __align__(16) unsigned short Wls[COLT * 2048];
    int tid = threadIdx.x;
    {
        const float4* src = (const float4*)Wg;
        float4* dst = (float4*)Wls;
#pragma unroll
        for (int i = 0; i < COLT; ++i) dst[tid + i * 256] = src[tid + i * 256];
    }
    __syncthreads();
    int w = tid >> 6, lane = tid & 63;
    int n = lane & 15, q = lane >> 4;
    int row0 = blockIdx.x * 64 + w * 16;
    int ar = row0 + n; ar = ar < N ? ar : N - 1;   // clamp: OOB rows harmless
    f32x4 acc[COLT];
#pragma unroll
    for (int t = 0; t < COLT; ++t) acc[t] = (f32x4){0.f, 0.f, 0.f, 0.f};
    const unsigned short* arow = A + (size_t)ar * 128;
#pragma unroll
    for (int ks = 0; ks < 4; ++ks) {
        bfrag a = *reinterpret_cast<const bfrag*>(arow + ks * 32 + q * 8);
#pragma unroll
        for (int t = 0; t < COLT; ++t) {
            bfrag b = *reinterpret_cast<const bfrag*>(&Wls[((t * 4 + ks) * 64 + lane) * 8]);
            acc[t] = __builtin_amdgcn_mfma_f32_16x16x32_bf16(a, b, acc[t], 0, 0, 0);
        }
    }
    if (ES) {
        float asv[COLT], adv[COLT];
#pragma unroll
        for (int t = 0; t < COLT; ++t) {
            int c = t * 16 + n;
            asv[t] = (c < cols) ? as_f[c] : 0.f;
            adv[t] = (c < cols) ? ad_f[c] : 0.f;
        }
#pragma unroll
        for (int r = 0; r < 4; ++r) {
            float pe[HEADS], pd[HEADS];
#pragma unroll
            for (int h = 0; h < HEADS; ++h) { pe[h] = 0.f; pd[h] = 0.f; }
#pragma unroll
            for (int t = 0; t < COLT; ++t) {
                int h = (HEADS == 4) ? (t >> 1) : 0;
                pe[h] = fmaf(acc[t][r], asv[t], pe[h]);
                pd[h] = fmaf(acc[t][r], adv[t], pd[h]);
            }
#pragma unroll
            for (int h = 0; h < HEADS; ++h) {
#pragma unroll
                for (int o = 1; o < 16; o <<= 1) {
                    pe[h] += __shfl_xor(pe[h], o, 64);
                    pd[h] += __shfl_xor(pd[h], o, 64);
                }
            }
            int row = row0 + q * 4 + r;
            if (n == 0 && row < N) {
#pragma unroll
                for (int h = 0; h < HEADS; ++h) {
                    es[(size_t)row * HEADS + h] = pe[h];
                    ed[(size_t)row * HEADS + h] = pd[h];
                }
            }
        }
    }
#pragma unroll
    for (int t = 0; t < COLT; ++t) {
        int col = t * 16 + n;
        if (col < cols) {
#pragma unroll
            for (int r = 0; r < 4; ++r) {
                int row = row0 + q * 4 + r;
                if (row < N) {
                    float v = acc[t][r];
                    out[(size_t)row * ldc + col] = (sizeof(OT) == 2) ? (OT)f2b(v) : (OT)v;
                }
            }
        }
    }
}

// W1 + Wres in one pass (A read once)
__global__ __launch_bounds__(256) void gemm_dual(
    const unsigned short* __restrict__ Araw, const unsigned short* __restrict__ Acvt,
    const int* __restrict__ flag,
    const unsigned short* __restrict__ Wg1, const unsigned short* __restrict__ WgR,
    const float* __restrict__ as_f, const float* __restrict__ ad_f,
    unsigned short* __restrict__ xwb, float* __restrict__ resf,
    float* __restrict__ es, float* __restrict__ ed, int N) {
    __shared__ __align__(16) unsigned short Wls[16 * 2048];
    int tid = threadIdx.x;
    {
        const float4* s1 = (const float4*)Wg1;
        const float4* s2 = (const float4*)WgR;
        float4* dst = (float4*)Wls;
#pragma unroll
        for (int i = 0; i < 8; ++i) dst[tid + i * 256] = s1[tid + i * 256];
#pragma unroll
        for (int i = 0; i < 8; ++i) dst[2048 + tid + i * 256] = s2[tid + i * 256];
    }
    const unsigned short* A = (*flag) ? Araw : Acvt;
    __syncthreads();
    int w = tid >> 6, lane = tid & 63;
    int n = lane & 15, q = lane >> 4;
    int row0 = blockIdx.x * 64 + w * 16;
    int ar = row0 + n; ar = ar < N ? ar : N - 1;
    f32x4 acc[16];
#pragma unroll
    for (int t = 0; t < 16; ++t) acc[t] = (f32x4){0.f, 0.f, 0.f, 0.f};
    const unsigned short* arow = A + (size_t)ar * 128;
#pragma unroll
    for (int ks = 0; ks < 4; ++ks) {
        bfrag a = *reinterpret_cast<const bfrag*>(arow + ks * 32 + q * 8);
#pragma unroll
        for (int t = 0; t < 8; ++t) {
            bfrag b = *reinterpret_cast<const bfrag*>(&Wls[((t * 4 + ks) * 64 + lane) * 8]);
            acc[t] = __builtin_amdgcn_mfma_f32_16x16x32_bf16(a, b, acc[t], 0, 0, 0);
        }
#pragma unroll
        for (int t = 0; t < 8; ++t) {
            bfrag b = *reinterpret_cast<const bfrag*>(&Wls[16384 + ((t * 4 + ks) * 64 + lane) * 8]);
            acc[8 + t] = __builtin_amdgcn_mfma_f32_16x16x32_bf16(a, b, acc[8 + t], 0, 0, 0);
        }
    }
    float asv[8], adv[8];
#pragma unroll
    for (int t = 0; t < 8; ++t) {
        int c = t * 16 + n;
        asv[t] = as_f[c];
        adv[t] = ad_f[c];
    }
#pragma unroll
    for (int r = 0; r < 4; ++r) {
        float pe[4] = {0.f, 0.f, 0.f, 0.f}, pd[4] = {0.f, 0.f, 0.f, 0.f};
#pragma unroll
        for (int t = 0; t < 8; ++t) {
            int h = t >> 1;
            pe[h] = fmaf(acc[t][r], asv[t], pe[h]);
            pd[h] = fmaf(acc[t][r], adv[t], pd[h]);
        }
#pragma unroll
        for (int h = 0; h < 4; ++h) {
#pragma unroll
            for (int o = 1; o < 16; o <<= 1) {
                pe[h] += __shfl_xor(pe[h], o, 64);
                pd[h] += __shfl_xor(pd[h], o, 64);
            }
        }
        int row = row0 + q * 4 + r;
        if (n == 0 && row < N) {
#pragma unroll
            for (int h = 0; h < 4; ++h) {
                es[(size_t)row * 4 + h] = pe[h];
                ed[(size_t)row * 4 + h] = pd[h];
            }
        }
    }
#pragma unroll
    for (int t = 0; t < 8; ++t) {
        int col = t * 16 + n;
#pragma unroll
        for (int r = 0; r < 4; ++r) {
            int row = row0 + q * 4 + r;
            if (row < N) {
                xwb[(size_t)row * 128 + col] = f2b(acc[t][r]);
                resf[(size_t)row * 128 + col] = acc[8 + t][r];
            }
        }
    }
}

// ---------------- agg layers 1-2 + fused BN/bias/residual/ELU ----------------
template <bool WF32>
__global__ __launch_bounds__(256) void agg128_fused(
    const unsigned short* __restrict__ xwb, const float* __restrict__ es,
    const float* __restrict__ ed, const int* __restrict__ row_ptr,
    const int* __restrict__ csr, const float* __restrict__ bnsc,
    const float* __restrict__ bnsh, const float* __restrict__ res,
    float* __restrict__ outf, unsigned short* __restrict__ outb, int N) {
    int w = threadIdx.x >> 6, lane = threadIdx.x & 63;
    int node = blockIdx.x * 4 + w;
    if (node >= N) return;
    int h = lane >> 4;
    int i16 = lane & 15;
    int base = lane & 48;
    int c0 = lane * 2;
    float edl = ed[node * 4 + h];
    int start = row_ptr[node], end = row_ptr[node + 1];
    float den = 0.f, a0 = 0.f, a1 = 0.f;
    for (int jb = start; jb < end; jb += 16) {
        int cnt = end - jb; cnt = cnt < 16 ? cnt : 16;
        int sv = csr[jb + (i16 < cnt ? i16 : 0)];
        float wgl = 0.f;
        if (i16 < cnt) {
            float e = es[sv * 4 + h] + edl;
            e = e > 0.f ? e : 0.2f * e;
            wgl = __expf(e);
        }
        float d = wgl;
        d += __shfl_xor(d, 1, 64);
        d += __shfl_xor(d, 2, 64);
        d += __shfl_xor(d, 4, 64);
        d += __shfl_xor(d, 8, 64);
        den += d;
        for (int j4 = 0; j4 < cnt; j4 += 4) {
#pragma unroll
            for (int u = 0; u < 4; ++u) {
                int j = j4 + u;
                int s = __shfl(sv, j, 64);
                float wg = __shfl(wgl, base + j, 64);   // 0 for padded slots
                unsigned uu = *(const unsigned*)(xwb + (size_t)s * 128 + c0);
                a0 = fmaf(wg, __uint_as_float(uu << 16), a0);
                a1 = fmaf(wg, __uint_as_float(uu & 0xffff0000u), a1);
            }
        }
    }
    float inv = 1.f / den;
    float2 sc = *(const float2*)(bnsc + c0);
    float2 sh = *(const float2*)(bnsh + c0);
    float2 rr = *(const float2*)(res + (size_t)node * 128 + c0);
    float v0 = fmaf(a0 * inv, sc.x, sh.x) + rr.x;
    float v1 = fmaf(a1 * inv, sc.y, sh.y) + rr.y;
    v0 = v0 > 0.f ? v0 : expm1f(v0);
    v1 = v1 > 0.f ? v1 : expm1f(v1);
    if (WF32) *(float2*)(outf + (size_t)node * 128 + c0) = make_float2(v0, v1);
    unsigned pk = (unsigned)f2b(v0) | ((unsigned)f2b(v1) << 16);
    *(unsigned*)(outb + (size_t)node * 128 + c0) = pk;
}

// ---------------- layer-3 agg (H=1, 40ch) ----------------
__global__ __launch_bounds__(256) void agg40_kernel(
    const unsigned short* __restrict__ xw3b, const float* __restrict__ es3,
    const float* __restrict__ ed3, const int* __restrict__ row_ptr,
    const int* __restrict__ csr, const float* __restrict__ b3,
    void* __restrict__ out, const int* __restrict__ flag, int N) {
    int w = threadIdx.x >> 6, lane = threadIdx.x & 63;
    int node = blockIdx.x * 4 + w;
    if (node >= N) return;
    int i16 = lane & 15;
    int g = lane >= 40 ? 2 : (lane >= 20 ? 1 : 0);
    int cp = lane - g * 20;
    int c0 = cp * 2; c0 = c0 > 38 ? 38 : c0;
    float edl = ed3[node];
    int start = row_ptr[node], end = row_ptr[node + 1];
    float den = 0.f, a0 = 0.f, a1 = 0.f;
    for (int jb = start; jb < end; jb += 16) {
        int cnt = end - jb; cnt = cnt < 16 ? cnt : 16;
        int sv = csr[jb + (i16 < cnt ? i16 : 0)];
        float wgl = 0.f;
        if (i16 < cnt) {
            float e = es3[sv] + edl;
            e = e > 0.f ? e : 0.2f * e;
            wgl = __expf(e);
        }
        float d = wgl;
        d += __shfl_xor(d, 1, 64);
        d += __shfl_xor(d, 2, 64);
        d += __shfl_xor(d, 4, 64);
        d += __shfl_xor(d, 8, 64);
        den += d;
        for (int j = 0; j < cnt; j += 3) {
            int slot = j + g;
            int sl = slot < 15 ? slot : 15;
            int s = __shfl(sv, sl, 64);
            float wg = __shfl(wgl, sl, 64);
            if (slot >= cnt) wg = 0.f;
            unsigned uu = *(const unsigned*)(xw3b + (size_t)s * 40 + c0);
            a0 = fmaf(wg, __uint_as_float(uu << 16), a0);
            a1 = fmaf(wg, __uint_as_float(uu & 0xffff0000u), a1);
        }
    }
    float t0 = __shfl(a0, (lane + 20) & 63, 64);
    float t1 = __shfl(a0, (lane + 40) & 63, 64);
    float u0 = __shfl(a1, (lane + 20) & 63, 64);
    float u1 = __shfl(a1, (lane + 40) & 63, 64);
    a0 += t0 + t1;
    a1 += u0 + u1;
    if (lane < 20) {
        float inv = 1.f / den;
        float v0 = a0 * inv + b3[c0];
        float v1 = a1 * inv + b3[c0 + 1];
        size_t eoff = (size_t)node * 40 + c0;
        if (*flag) {
            unsigned pk = (unsigned)f2b(v0) | ((unsigned)f2b(v1) << 16);
            *(unsigned*)((unsigned short*)out + eoff) = pk;
        } else {
            *(float2*)((float*)out + eoff) = make_float2(v0, v1);
        }
    }
}

extern "C" void kernel_launch(void* const* d_in, const int* in_sizes, int n_in,
                              void* d_out, int out_size, void* d_ws, size_t ws_size,
                              hipStream_t stream) {
    (void)n_in; (void)out_size; (void)ws_size;
    const int N = in_sizes[0] / 128;
    const int E = in_sizes[1] / 2;
    const int EPN = E + N;
    const int NB = (N + 255) / 256;
    char* base = (char*)d_ws;
    size_t off = 0;
    auto alloc = [&](size_t bytes) -> char* {
        char* p = base + off;
        off = (off + bytes + 255) & ~(size_t)255;
        return p;
    };
    int* flag = (int*)alloc(4);
    int* deg = (int*)alloc((size_t)N * 4);
    int* row_ptr = (int*)alloc((size_t)(N + 1) * 4);
    int* pos = (int*)alloc((size_t)N * 4);
    int* bsum = (int*)alloc((size_t)NB * 4);
    int* boff = (int*)alloc((size_t)NB * 4);
    int* csr = (int*)alloc((size_t)EPN * 4);
    float* wc = (float*)alloc((size_t)56184 * 4);
    float* bnsc1 = (float*)alloc(512); float* bnsh1 = (float*)alloc(512);
    float* bnsc2 = (float*)alloc(512); float* bnsh2 = (float*)alloc(512);
    unsigned short* Wl1 = (unsigned short*)alloc(32768);
    unsigned short* Wl2 = (unsigned short*)alloc(32768);
    unsigned short* WlR = (unsigned short*)alloc(32768);
    unsigned short* Wl3 = (unsigned short*)alloc(12288);
    unsigned short* xb = (unsigned short*)alloc((size_t)N * 128 * 2);
    unsigned short* xwb = (unsigned short*)alloc((size_t)N * 128 * 2);  // also xw3b
    unsigned short* h1b = (unsigned short*)alloc((size_t)N * 128 * 2);
    float* h1 = (float*)alloc((size_t)N * 128 * 4);
    float* resf = (float*)alloc((size_t)N * 128 * 4);  // layer1 residual; later h2b bf16
    float* es = (float*)alloc((size_t)N * 4 * 4);
    float* ed = (float*)alloc((size_t)N * 4 * 4);

    const int* ei = (const int*)d_in[1];

    float* W1 = wc;            float* AS1 = wc + 16384; float* AD1 = wc + 16512; float* B1 = wc + 16640;
    float* W2 = wc + 16768;    float* AS2 = wc + 33152; float* AD2 = wc + 33280; float* B2 = wc + 33408;
    float* W3 = wc + 33536;    float* AS3 = wc + 38656; float* AD3 = wc + 38696; float* B3 = wc + 38736;
    float* WR = wc + 38776;
    float* G1 = wc + 55160; float* BE1 = wc + 55288; float* M1 = wc + 55416; float* V1 = wc + 55544;
    float* G2 = wc + 55672; float* BE2 = wc + 55800; float* M2 = wc + 55928; float* V2 = wc + 56056;

    hipMemsetAsync(deg, 0, (size_t)N * 4, stream);
    detect_kernel<<<1, THREADS, 0, stream>>>((const unsigned short*)d_in[0], 4096, flag);

    ConvArgs ca;
    const int idxs[21] = {2, 3, 4, 5, 6, 7, 8, 9, 10, 11, 12, 13, 14, 15, 16, 17, 18, 19, 20, 21, 22};
    float* dsts[21] = {W1, AS1, AD1, B1, W2, AS2, AD2, B2, W3, AS3, AD3, B3, WR,
                       G1, BE1, M1, V1, G2, BE2, M2, V2};
    int p = 0;
    for (int t = 0; t < 21; t++) {
        ca.src[t] = d_in[idxs[t]];
        ca.dst[t] = dsts[t];
        ca.prefix[t] = p;
        p += in_sizes[idxs[t]];
    }
    ca.prefix[21] = p;
    convert_kernel<<<(p + THREADS - 1) / THREADS, THREADS, 0, stream>>>(ca, flag, p);

    xconv_kernel<<<(N * 128 + THREADS - 1) / THREADS, THREADS, 0, stream>>>(
        (const float*)d_in[0], flag, xb, N * 128);
    wtf_all<<<27, THREADS, 0, stream>>>(W1, W2, WR, W3, Wl1, Wl2, WlR, Wl3);
    bnprep_kernel<<<1, THREADS, 0, stream>>>(G1, BE1, M1, V1, B1, G2, BE2, M2, V2, B2,
                                             bnsc1, bnsh1, bnsc2, bnsh2);

    count_kernel<<<(EPN + THREADS - 1) / THREADS, THREADS, 0, stream>>>(ei, deg, E, N);
    bsum_kernel<<<NB, 256, 0, stream>>>(deg, bsum, N);
    bscan_kernel<<<1, 1024, 0, stream>>>(bsum, boff, NB);
    scanw_kernel<<<NB, 256, 0, stream>>>(deg, boff, row_ptr, pos, N);
    scatter_kernel<<<(EPN + THREADS - 1) / THREADS, THREADS, 0, stream>>>(ei, pos, csr, E, N);

    int gemmGrid = (N + 63) / 64;
    int aggGrid = (N + 3) / 4;

    // layer 1 (W1 + Wres fused GEMM; BN/bias/res/ELU fused into agg epilogue)
    gemm_dual<<<gemmGrid, 256, 0, stream>>>((const unsigned short*)d_in[0], xb, flag,
                                            Wl1, WlR, AS1, AD1, xwb, resf, es, ed, N);
    agg128_fused<true><<<aggGrid, 256, 0, stream>>>(xwb, es, ed, row_ptr, csr,
                                                    bnsc1, bnsh1, resf, h1, h1b, N);
    // layer 2
    gemm_mfma<8, 4, true, unsigned short><<<gemmGrid, 256, 0, stream>>>(
        h1b, Wl2, AS2, AD2, xwb, 128, 128, es, ed, N);
    unsigned short* h2b = (unsigned short*)resf;
    agg128_fused<false><<<aggGrid, 256, 0, stream>>>(xwb, es, ed, row_ptr, csr,
                                                     bnsc2, bnsh2, h1, nullptr, h2b, N);
    // layer 3
    gemm_mfma<3, 1, true, unsigned short><<<gemmGrid, 256, 0, stream>>>(
        h2b, Wl3, AS3, AD3, xwb, 40, 40, es, ed, N);
    agg40_kernel<<<aggGrid, 256, 0, stream>>>(xwb, es, ed, row_ptr, csr, B3, d_out, flag, N);
}

// Round 5
// 300.638 us; speedup vs baseline: 2.6642x; 1.0281x over previous
//
#include <hip/hip_runtime.h>
#include <hip/hip_bf16.h>

#define THREADS 256

typedef __attribute__((ext_vector_type(8))) short bfrag;     // 8 bf16 = 4 VGPR
typedef __attribute__((ext_vector_type(4))) float f32x4;     // MFMA accumulator

__device__ inline unsigned short f2b(float v) {
    __hip_bfloat16 b = __float2bfloat16(v);
    return *reinterpret_cast<unsigned short*>(&b);
}
__device__ inline float b2f(unsigned short u) {
    return __uint_as_float(((unsigned)u) << 16);
}
// read element `off` from raw input (bf16 or fp32 per flag)
__device__ inline float rdv(const void* p, int off, bool isbf) {
    return isbf ? b2f(((const unsigned short*)p)[off]) : ((const float*)p)[off];
}

// ---------------- dtype detection (bf16 vs fp32 inputs) ----------------
__global__ void detect_kernel(const unsigned short* __restrict__ x, int n, int* flag) {
    __shared__ int cnt;
    if (threadIdx.x == 0) cnt = 0;
    __syncthreads();
    int local = 0;
    for (int i = threadIdx.x; i < n; i += THREADS) {
        unsigned ex = (x[i] >> 7) & 0xFF;
        if (ex == 0xFF || ex >= 134 || (ex > 0 && ex <= 100)) local++;
    }
    atomicAdd(&cnt, local);
    __syncthreads();
    if (threadIdx.x == 0) *flag = (cnt * 8 > n) ? 0 : 1;  // 1 = bf16
}

// ---------------- fused prep: W->fragment-order bf16, BN fold, small converts, xconv ----
struct InPtrs { const void* p[23]; };

__global__ void prep_kernel(InPtrs in, const int* __restrict__ flag,
                            unsigned short* __restrict__ Wl1, unsigned short* __restrict__ Wl2,
                            unsigned short* __restrict__ WlR, unsigned short* __restrict__ Wl3,
                            float* __restrict__ bnsc1, float* __restrict__ bnsh1,
                            float* __restrict__ bnsc2, float* __restrict__ bnsh2,
                            float* __restrict__ AS1f, float* __restrict__ AD1f,
                            float* __restrict__ AS2f, float* __restrict__ AD2f,
                            float* __restrict__ AS3f, float* __restrict__ AD3f,
                            float* __restrict__ B3f, unsigned short* __restrict__ xb, int N) {
    bool isbf = (*flag != 0);
    int b = blockIdx.x;
    if (b < 27) {
        // W [128,cols] raw -> bf16 fragment order:
        // out[((t*4+ks)*64+lane)*8+j] = W[ks*32+(lane>>4)*8+j][t*16+(lane&15)]
        const void* Wv; unsigned short* o; int cols, tt;
        if (b < 8)       { Wv = in.p[2];  o = Wl1; cols = 128; tt = b; }
        else if (b < 16) { Wv = in.p[6];  o = Wl2; cols = 128; tt = b - 8; }
        else if (b < 24) { Wv = in.p[14]; o = WlR; cols = 128; tt = b - 16; }
        else             { Wv = in.p[10]; o = Wl3; cols = 40;  tt = b - 24; }
        int id = tt * 256 + threadIdx.x;
        int t = id >> 8, ks = (id >> 6) & 3, l = id & 63;
        int q = l >> 4, n = l & 15;
        int c = t * 16 + n;
#pragma unroll
        for (int j = 0; j < 8; ++j) {
            int k = ks * 32 + q * 8 + j;
            float v = (c < cols) ? rdv(Wv, k * cols + c, isbf) : 0.f;
            o[id * 8 + j] = f2b(v);
        }
    } else if (b == 27) {
        int c = threadIdx.x;
        if (c < 128) {
            float s = rdv(in.p[15], c, isbf) * rsqrtf(rdv(in.p[18], c, isbf) + 1e-5f);
            bnsc1[c] = s;
            bnsh1[c] = rdv(in.p[16], c, isbf) - rdv(in.p[17], c, isbf) * s +
                       rdv(in.p[5], c, isbf) * s;
            AS1f[c] = rdv(in.p[3], c, isbf);
            AD1f[c] = rdv(in.p[4], c, isbf);
            AS2f[c] = rdv(in.p[7], c, isbf);
            AD2f[c] = rdv(in.p[8], c, isbf);
        } else {
            int d = c - 128;
            float s = rdv(in.p[19], d, isbf) * rsqrtf(rdv(in.p[22], d, isbf) + 1e-5f);
            bnsc2[d] = s;
            bnsh2[d] = rdv(in.p[20], d, isbf) - rdv(in.p[21], d, isbf) * s +
                       rdv(in.p[9], d, isbf) * s;
            if (d < 40) {
                AS3f[d] = rdv(in.p[11], d, isbf);
                AD3f[d] = rdv(in.p[12], d, isbf);
                B3f[d] = rdv(in.p[13], d, isbf);
            }
        }
    } else {
        if (isbf) return;  // bf16 path: gemm reads d_in[0] raw
        const float* xf = (const float*)in.p[0];
        int total = N * 128;
        int stride = (gridDim.x - 28) * 256;
        for (int i = (b - 28) * 256 + threadIdx.x; i < total; i += stride) xb[i] = f2b(xf[i]);
    }
}

// ---------------- CSR build (parallel 3-stage scan) ----------------
__global__ void count_kernel(const int* __restrict__ ei, int* __restrict__ deg, int E, int N) {
    int e = blockIdx.x * THREADS + threadIdx.x;
    if (e >= E + N) return;
    int d = (e < E) ? ei[E + e] : (e - E);
    atomicAdd(&deg[d], 1);
}

__global__ void bsum_kernel(const int* __restrict__ deg, int* __restrict__ bsum, int N) {
    int idx = blockIdx.x * 256 + threadIdx.x;
    int lane = threadIdx.x & 63, wv = threadIdx.x >> 6;
    int v = (idx < N) ? deg[idx] : 0;
#pragma unroll
    for (int o = 1; o < 64; o <<= 1) v += __shfl_xor(v, o, 64);
    __shared__ int ws[4];
    if (lane == 0) ws[wv] = v;
    __syncthreads();
    if (threadIdx.x == 0) bsum[blockIdx.x] = ws[0] + ws[1] + ws[2] + ws[3];
}

__global__ __launch_bounds__(1024) void bscan_kernel(const int* __restrict__ bsum,
                                                     int* __restrict__ boff, int nb) {
    __shared__ int ws[16];
    int tid = threadIdx.x, lane = tid & 63, wv = tid >> 6;
    int v = (tid < nb) ? bsum[tid] : 0;
    int sc = v;
#pragma unroll
    for (int o = 1; o < 64; o <<= 1) {
        int t = __shfl_up(sc, o, 64);
        if (lane >= o) sc += t;
    }
    if (lane == 63) ws[wv] = sc;
    __syncthreads();
    int add = 0;
#pragma unroll
    for (int k = 0; k < 16; ++k) add += (k < wv) ? ws[k] : 0;
    if (tid < nb) boff[tid] = add + sc - v;
}

__global__ void scanw_kernel(const int* __restrict__ deg, const int* __restrict__ boff,
                             int* __restrict__ row_ptr, int* __restrict__ pos, int N) {
    int idx = blockIdx.x * 256 + threadIdx.x;
    int lane = threadIdx.x & 63, wv = threadIdx.x >> 6;
    int v = (idx < N) ? deg[idx] : 0;
    int sc = v;
#pragma unroll
    for (int o = 1; o < 64; o <<= 1) {
        int t = __shfl_up(sc, o, 64);
        if (lane >= o) sc += t;
    }
    __shared__ int ws[4];
    if (lane == 63) ws[wv] = sc;
    __syncthreads();
    int add = boff[blockIdx.x];
#pragma unroll
    for (int k = 0; k < 4; ++k) add += (k < wv) ? ws[k] : 0;
    int excl = add + sc - v;
    if (idx < N) {
        pos[idx] = excl;
        row_ptr[idx + 1] = excl + v;
    }
    if (idx == 0) row_ptr[0] = 0;
}

__global__ void scatter_kernel(const int* __restrict__ ei, int* __restrict__ pos,
                               int* __restrict__ csr, int E, int N) {
    int e = blockIdx.x * THREADS + threadIdx.x;
    if (e >= E + N) return;
    int s, d;
    if (e < E) { s = ei[e]; d = ei[E + e]; }
    else { s = e - E; d = s; }
    int p = atomicAdd(&pos[d], 1);
    csr[p] = s;
}

// ---------------- MFMA GEMM: [N,128]bf16 @ [128,cols]bf16 ----------------
template <int COLT, int HEADS, bool ES>
__global__ __launch_bounds__(256) void gemm_mfma(
    const unsigned short* __restrict__ A, const unsigned short* __restrict__ Wg,
    const float* __restrict__ as_f, const float* __restrict__ ad_f,
    unsigned short* __restrict__ out, int ldc, int cols,
    float* __restrict__ es, float* __restrict__ ed, int N) {
    __shared__ __align__(16) unsigned short Wls[COLT * 2048];
    int tid = threadIdx.x;
    {
        const float4* src = (const float4*)Wg;
        float4* dst = (float4*)Wls;
#pragma unroll
        for (int i = 0; i < COLT; ++i) dst[tid + i * 256] = src[tid + i * 256];
    }
    __syncthreads();
    int w = tid >> 6, lane = tid & 63;
    int n = lane & 15, q = lane >> 4;
    int row0 = blockIdx.x * 64 + w * 16;
    int ar = row0 + n; ar = ar < N ? ar : N - 1;   // clamp: OOB rows harmless
    f32x4 acc[COLT];
#pragma unroll
    for (int t = 0; t < COLT; ++t) acc[t] = (f32x4){0.f, 0.f, 0.f, 0.f};
    const unsigned short* arow = A + (size_t)ar * 128;
#pragma unroll
    for (int ks = 0; ks < 4; ++ks) {
        bfrag a = *reinterpret_cast<const bfrag*>(arow + ks * 32 + q * 8);
#pragma unroll
        for (int t = 0; t < COLT; ++t) {
            bfrag b = *reinterpret_cast<const bfrag*>(&Wls[((t * 4 + ks) * 64 + lane) * 8]);
            acc[t] = __builtin_amdgcn_mfma_f32_16x16x32_bf16(a, b, acc[t], 0, 0, 0);
        }
    }
    if (ES) {
        float asv[COLT], adv[COLT];
#pragma unroll
        for (int t = 0; t < COLT; ++t) {
            int c = t * 16 + n;
            asv[t] = (c < cols) ? as_f[c] : 0.f;
            adv[t] = (c < cols) ? ad_f[c] : 0.f;
        }
#pragma unroll
        for (int r = 0; r < 4; ++r) {
            float pe[HEADS], pd[HEADS];
#pragma unroll
            for (int h = 0; h < HEADS; ++h) { pe[h] = 0.f; pd[h] = 0.f; }
#pragma unroll
            for (int t = 0; t < COLT; ++t) {
                int h = (HEADS == 4) ? (t >> 1) : 0;
                pe[h] = fmaf(acc[t][r], asv[t], pe[h]);
                pd[h] = fmaf(acc[t][r], adv[t], pd[h]);
            }
#pragma unroll
            for (int h = 0; h < HEADS; ++h) {
#pragma unroll
                for (int o = 1; o < 16; o <<= 1) {
                    pe[h] += __shfl_xor(pe[h], o, 64);
                    pd[h] += __shfl_xor(pd[h], o, 64);
                }
            }
            int row = row0 + q * 4 + r;
            if (n == 0 && row < N) {
#pragma unroll
                for (int h = 0; h < HEADS; ++h) {
                    es[(size_t)row * HEADS + h] = pe[h];
                    ed[(size_t)row * HEADS + h] = pd[h];
                }
            }
        }
    }
#pragma unroll
    for (int t = 0; t < COLT; ++t) {
        int col = t * 16 + n;
        if (col < cols) {
#pragma unroll
            for (int r = 0; r < 4; ++r) {
                int row = row0 + q * 4 + r;
                if (row < N) out[(size_t)row * ldc + col] = f2b(acc[t][r]);
            }
        }
    }
}

// W1 + Wres in one pass (A read once); both outputs bf16
__global__ __launch_bounds__(256) void gemm_dual(
    const unsigned short* __restrict__ Araw, const unsigned short* __restrict__ Acvt,
    const int* __restrict__ flag,
    const unsigned short* __restrict__ Wg1, const unsigned short* __restrict__ WgR,
    const float* __restrict__ as_f, const float* __restrict__ ad_f,
    unsigned short* __restrict__ xwb, unsigned short* __restrict__ resb,
    float* __restrict__ es, float* __restrict__ ed, int N) {
    __shared__ __align__(16) unsigned short Wls[16 * 2048];
    int tid = threadIdx.x;
    {
        const float4* s1 = (const float4*)Wg1;
        const float4* s2 = (const float4*)WgR;
        float4* dst = (float4*)Wls;
#pragma unroll
        for (int i = 0; i < 8; ++i) dst[tid + i * 256] = s1[tid + i * 256];
#pragma unroll
        for (int i = 0; i < 8; ++i) dst[2048 + tid + i * 256] = s2[tid + i * 256];
    }
    const unsigned short* A = (*flag) ? Araw : Acvt;
    __syncthreads();
    int w = tid >> 6, lane = tid & 63;
    int n = lane & 15, q = lane >> 4;
    int row0 = blockIdx.x * 64 + w * 16;
    int ar = row0 + n; ar = ar < N ? ar : N - 1;
    f32x4 acc[16];
#pragma unroll
    for (int t = 0; t < 16; ++t) acc[t] = (f32x4){0.f, 0.f, 0.f, 0.f};
    const unsigned short* arow = A + (size_t)ar * 128;
#pragma unroll
    for (int ks = 0; ks < 4; ++ks) {
        bfrag a = *reinterpret_cast<const bfrag*>(arow + ks * 32 + q * 8);
#pragma unroll
        for (int t = 0; t < 8; ++t) {
            bfrag b = *reinterpret_cast<const bfrag*>(&Wls[((t * 4 + ks) * 64 + lane) * 8]);
            acc[t] = __builtin_amdgcn_mfma_f32_16x16x32_bf16(a, b, acc[t], 0, 0, 0);
        }
#pragma unroll
        for (int t = 0; t < 8; ++t) {
            bfrag b = *reinterpret_cast<const bfrag*>(&Wls[16384 + ((t * 4 + ks) * 64 + lane) * 8]);
            acc[8 + t] = __builtin_amdgcn_mfma_f32_16x16x32_bf16(a, b, acc[8 + t], 0, 0, 0);
        }
    }
    float asv[8], adv[8];
#pragma unroll
    for (int t = 0; t < 8; ++t) {
        int c = t * 16 + n;
        asv[t] = as_f[c];
        adv[t] = ad_f[c];
    }
#pragma unroll
    for (int r = 0; r < 4; ++r) {
        float pe[4] = {0.f, 0.f, 0.f, 0.f}, pd[4] = {0.f, 0.f, 0.f, 0.f};
#pragma unroll
        for (int t = 0; t < 8; ++t) {
            int h = t >> 1;
            pe[h] = fmaf(acc[t][r], asv[t], pe[h]);
            pd[h] = fmaf(acc[t][r], adv[t], pd[h]);
        }
#pragma unroll
        for (int h = 0; h < 4; ++h) {
#pragma unroll
            for (int o = 1; o < 16; o <<= 1) {
                pe[h] += __shfl_xor(pe[h], o, 64);
                pd[h] += __shfl_xor(pd[h], o, 64);
            }
        }
        int row = row0 + q * 4 + r;
        if (n == 0 && row < N) {
#pragma unroll
            for (int h = 0; h < 4; ++h) {
                es[(size_t)row * 4 + h] = pe[h];
                ed[(size_t)row * 4 + h] = pd[h];
            }
        }
    }
#pragma unroll
    for (int t = 0; t < 8; ++t) {
        int col = t * 16 + n;
#pragma unroll
        for (int r = 0; r < 4; ++r) {
            int row = row0 + q * 4 + r;
            if (row < N) {
                xwb[(size_t)row * 128 + col] = f2b(acc[t][r]);
                resb[(size_t)row * 128 + col] = f2b(acc[8 + t][r]);
            }
        }
    }
}

// ---------------- agg layers 1-2 + fused BN/bias/residual/ELU ----------------
// wave/node; per 16-edge chunk ALL 16 row-gathers preloaded into registers
// (independent of softmax math -> 16 outstanding loads; tail dups are L1 hits).
__global__ __launch_bounds__(256) void agg128_fused(
    const unsigned short* __restrict__ xwb, const float* __restrict__ es,
    const float* __restrict__ ed, const int* __restrict__ row_ptr,
    const int* __restrict__ csr, const float* __restrict__ bnsc,
    const float* __restrict__ bnsh, const unsigned short* __restrict__ resb,
    unsigned short* __restrict__ outb, int N) {
    int w = threadIdx.x >> 6, lane = threadIdx.x & 63;
    int node = blockIdx.x * 4 + w;
    if (node >= N) return;
    int h = lane >> 4;
    int i16 = lane & 15;
    int base = lane & 48;
    int c0 = lane * 2;
    float edl = ed[node * 4 + h];
    int start = row_ptr[node], end = row_ptr[node + 1];
    float den = 0.f, a0 = 0.f, a1 = 0.f;
    for (int jb = start; jb < end; jb += 16) {
        int cnt = end - jb; cnt = cnt < 16 ? cnt : 16;
        int sv = csr[jb + (i16 < cnt ? i16 : 0)];
        unsigned uu[16];
#pragma unroll
        for (int u = 0; u < 16; ++u) {
            int s = __shfl(sv, u, 64);
            uu[u] = *(const unsigned*)(xwb + (size_t)s * 128 + c0);
        }
        float wgl = 0.f;
        if (i16 < cnt) {
            float e = es[sv * 4 + h] + edl;
            e = e > 0.f ? e : 0.2f * e;
            wgl = __expf(e);
        }
        float d = wgl;
        d += __shfl_xor(d, 1, 64);
        d += __shfl_xor(d, 2, 64);
        d += __shfl_xor(d, 4, 64);
        d += __shfl_xor(d, 8, 64);
        den += d;
#pragma unroll
        for (int u = 0; u < 16; ++u) {
            float wg = __shfl(wgl, base + u, 64);   // 0 for padded slots
            a0 = fmaf(wg, __uint_as_float(uu[u] << 16), a0);
            a1 = fmaf(wg, __uint_as_float(uu[u] & 0xffff0000u), a1);
        }
    }
    float inv = 1.f / den;
    float2 sc = *(const float2*)(bnsc + c0);
    float2 sh = *(const float2*)(bnsh + c0);
    unsigned ur = *(const unsigned*)(resb + (size_t)node * 128 + c0);
    float v0 = fmaf(a0 * inv, sc.x, sh.x) + __uint_as_float(ur << 16);
    float v1 = fmaf(a1 * inv, sc.y, sh.y) + __uint_as_float(ur & 0xffff0000u);
    v0 = v0 > 0.f ? v0 : expm1f(v0);
    v1 = v1 > 0.f ? v1 : expm1f(v1);
    unsigned pk = (unsigned)f2b(v0) | ((unsigned)f2b(v1) << 16);
    *(unsigned*)(outb + (size_t)node * 128 + c0) = pk;
}

// ---------------- layer-3 agg (H=1, 40ch): 6 preloaded gathers in flight ----------------
__global__ __launch_bounds__(256) void agg40_kernel(
    const unsigned short* __restrict__ xw3b, const float* __restrict__ es3,
    const float* __restrict__ ed3, const int* __restrict__ row_ptr,
    const int* __restrict__ csr, const float* __restrict__ b3,
    void* __restrict__ out, const int* __restrict__ flag, int N) {
    int w = threadIdx.x >> 6, lane = threadIdx.x & 63;
    int node = blockIdx.x * 4 + w;
    if (node >= N) return;
    int i16 = lane & 15;
    int g = lane >= 40 ? 2 : (lane >= 20 ? 1 : 0);
    int cp = lane - g * 20;
    int c0 = cp * 2; c0 = c0 > 38 ? 38 : c0;
    float edl = ed3[node];
    int start = row_ptr[node], end = row_ptr[node + 1];
    float den = 0.f, a0 = 0.f, a1 = 0.f;
    for (int jb = start; jb < end; jb += 16) {
        int cnt = end - jb; cnt = cnt < 16 ? cnt : 16;
        int sv = csr[jb + (i16 < cnt ? i16 : 0)];
        unsigned uu[6];
#pragma unroll
        for (int t = 0; t < 6; ++t) {
            int slot = 3 * t + g; slot = slot < 15 ? slot : 15;
            int s = __shfl(sv, slot, 64);
            uu[t] = *(const unsigned*)(xw3b + (size_t)s * 40 + c0);
        }
        float wgl = 0.f;
        if (i16 < cnt) {
            float e = es3[sv] + edl;
            e = e > 0.f ? e : 0.2f * e;
            wgl = __expf(e);
        }
        float d = wgl;
        d += __shfl_xor(d, 1, 64);
        d += __shfl_xor(d, 2, 64);
        d += __shfl_xor(d, 4, 64);
        d += __shfl_xor(d, 8, 64);
        den += d;
#pragma unroll
        for (int t = 0; t < 6; ++t) {
            int slot = 3 * t + g;
            int sl = slot < 15 ? slot : 15;
            float wg = __shfl(wgl, sl, 64);
            if (slot >= cnt) wg = 0.f;
            a0 = fmaf(wg, __uint_as_float(uu[t] << 16), a0);
            a1 = fmaf(wg, __uint_as_float(uu[t] & 0xffff0000u), a1);
        }
    }
    float t0 = __shfl(a0, (lane + 20) & 63, 64);
    float t1 = __shfl(a0, (lane + 40) & 63, 64);
    float u0 = __shfl(a1, (lane + 20) & 63, 64);
    float u1 = __shfl(a1, (lane + 40) & 63, 64);
    a0 += t0 + t1;
    a1 += u0 + u1;
    if (lane < 20) {
        float inv = 1.f / den;
        float v0 = a0 * inv + b3[c0];
        float v1 = a1 * inv + b3[c0 + 1];
        size_t eoff = (size_t)node * 40 + c0;
        if (*flag) {
            unsigned pk = (unsigned)f2b(v0) | ((unsigned)f2b(v1) << 16);
            *(unsigned*)((unsigned short*)out + eoff) = pk;
        } else {
            *(float2*)((float*)out + eoff) = make_float2(v0, v1);
        }
    }
}

extern "C" void kernel_launch(void* const* d_in, const int* in_sizes, int n_in,
                              void* d_out, int out_size, void* d_ws, size_t ws_size,
                              hipStream_t stream) {
    (void)n_in; (void)out_size; (void)ws_size;
    const int N = in_sizes[0] / 128;
    const int E = in_sizes[1] / 2;
    const int EPN = E + N;
    const int NB = (N + 255) / 256;
    char* base = (char*)d_ws;
    size_t off = 0;
    auto alloc = [&](size_t bytes) -> char* {
        char* p = base + off;
        off = (off + bytes + 255) & ~(size_t)255;
        return p;
    };
    int* flag = (int*)alloc(4);
    int* deg = (int*)alloc((size_t)N * 4);
    int* row_ptr = (int*)alloc((size_t)(N + 1) * 4);
    int* pos = (int*)alloc((size_t)N * 4);
    int* bsum = (int*)alloc((size_t)NB * 4);
    int* boff = (int*)alloc((size_t)NB * 4);
    int* csr = (int*)alloc((size_t)EPN * 4);
    float* bnsc1 = (float*)alloc(512); float* bnsh1 = (float*)alloc(512);
    float* bnsc2 = (float*)alloc(512); float* bnsh2 = (float*)alloc(512);
    float* AS1f = (float*)alloc(512); float* AD1f = (float*)alloc(512);
    float* AS2f = (float*)alloc(512); float* AD2f = (float*)alloc(512);
    float* AS3f = (float*)alloc(256); float* AD3f = (float*)alloc(256);
    float* B3f = (float*)alloc(256);
    unsigned short* Wl1 = (unsigned short*)alloc(32768);
    unsigned short* Wl2 = (unsigned short*)alloc(32768);
    unsigned short* WlR = (unsigned short*)alloc(32768);
    unsigned short* Wl3 = (unsigned short*)alloc(12288);
    unsigned short* xb = (unsigned short*)alloc((size_t)N * 128 * 2);
    unsigned short* xwb = (unsigned short*)alloc((size_t)N * 128 * 2);  // also xw3b
    unsigned short* h1b = (unsigned short*)alloc((size_t)N * 128 * 2);
    unsigned short* resb = (unsigned short*)alloc((size_t)N * 128 * 2); // later h2b
    float* es = (float*)alloc((size_t)N * 4 * 4);
    float* ed = (float*)alloc((size_t)N * 4 * 4);

    const int* ei = (const int*)d_in[1];

    hipMemsetAsync(deg, 0, (size_t)N * 4, stream);
    detect_kernel<<<1, THREADS, 0, stream>>>((const unsigned short*)d_in[0], 4096, flag);

    InPtrs ip;
    for (int t = 0; t < 23; t++) ip.p[t] = d_in[t];
    prep_kernel<<<28 + 2048, THREADS, 0, stream>>>(ip, flag, Wl1, Wl2, WlR, Wl3,
                                                   bnsc1, bnsh1, bnsc2, bnsh2,
                                                   AS1f, AD1f, AS2f, AD2f,
                                                   AS3f, AD3f, B3f, xb, N);

    count_kernel<<<(EPN + THREADS - 1) / THREADS, THREADS, 0, stream>>>(ei, deg, E, N);
    bsum_kernel<<<NB, 256, 0, stream>>>(deg, bsum, N);
    bscan_kernel<<<1, 1024, 0, stream>>>(bsum, boff, NB);
    scanw_kernel<<<NB, 256, 0, stream>>>(deg, boff, row_ptr, pos, N);
    scatter_kernel<<<(EPN + THREADS - 1) / THREADS, THREADS, 0, stream>>>(ei, pos, csr, E, N);

    int gemmGrid = (N + 63) / 64;
    int aggGrid = (N + 3) / 4;

    // layer 1 (W1 + Wres fused GEMM; BN/bias/res/ELU fused into agg epilogue)
    gemm_dual<<<gemmGrid, 256, 0, stream>>>((const unsigned short*)d_in[0], xb, flag,
                                            Wl1, WlR, AS1f, AD1f, xwb, resb, es, ed, N);
    agg128_fused<<<aggGrid, 256, 0, stream>>>(xwb, es, ed, row_ptr, csr,
                                              bnsc1, bnsh1, resb, h1b, N);
    // layer 2
    gemm_mfma<8, 4, true><<<gemmGrid, 256, 0, stream>>>(
        h1b, Wl2, AS2f, AD2f, xwb, 128, 128, es, ed, N);
    unsigned short* h2b = resb;  // resb free after layer-1 agg
    agg128_fused<<<aggGrid, 256, 0, stream>>>(xwb, es, ed, row_ptr, csr,
                                              bnsc2, bnsh2, h1b, h2b, N);
    // layer 3
    gemm_mfma<3, 1, true><<<gemmGrid, 256, 0, stream>>>(
        h2b, Wl3, AS3f, AD3f, xwb, 40, 40, es, ed, N);
    agg40_kernel<<<aggGrid, 256, 0, stream>>>(xwb, es, ed, row_ptr, csr, B3f, d_out, flag, N);
}